// Round 1
// baseline (2001.456 us; speedup 1.0000x reference)
//
#include <hip/hip_runtime.h>
#include <cstdint>

// GNN GATv2 x3 + mean-pool + MLP.  f32 throughout.
// Constants from the reference problem:
constexpr int GNUM = 128;   // graphs
// IN=16, HID=32, HEADS=4, EDIM=8, OUT=4, HC=128

// ---------------------------------------------------------------- setup kernels

__global__ __launch_bounds__(256) void hist_kernel(const int* __restrict__ dst,
                                                   int* __restrict__ cnt, int E) {
  int i = blockIdx.x * 256 + threadIdx.x;
  if (i < E) atomicAdd(&cnt[dst[i]], 1);
}

__global__ __launch_bounds__(1024) void scan_kernel(const int* __restrict__ cnt,
                                                    int* __restrict__ row_ptr,
                                                    int* __restrict__ fill, int n) {
  __shared__ int part[1024];
  int t = threadIdx.x;
  int chunk = (n + 1023) / 1024;
  int lo = t * chunk;
  if (lo > n) lo = n;
  int hi = lo + chunk;
  if (hi > n) hi = n;
  int s = 0;
  for (int i = lo; i < hi; i++) s += cnt[i];
  part[t] = s;
  __syncthreads();
  for (int off = 1; off < 1024; off <<= 1) {
    int v = (t >= off) ? part[t - off] : 0;
    __syncthreads();
    part[t] += v;
    __syncthreads();
  }
  int run = (t == 0) ? 0 : part[t - 1];
  for (int i = lo; i < hi; i++) {
    row_ptr[i] = run;
    fill[i] = run;
    run += cnt[i];
  }
  if (t == 0) row_ptr[n] = part[1023];
}

__global__ __launch_bounds__(256) void scatter_kernel(const int* __restrict__ src,
                                                      const int* __restrict__ dst,
                                                      int* __restrict__ fill,
                                                      int* __restrict__ csr_src,
                                                      int* __restrict__ csr_eid, int E) {
  int i = blockIdx.x * 256 + threadIdx.x;
  if (i >= E) return;
  int d = dst[i];
  int p = atomicAdd(&fill[d], 1);
  csr_src[p] = src[i];
  csr_eid[p] = i;
}

// loop_attr[i] = mean of incoming edge_attr (fill_value='mean'), 0 if no in-edges
__global__ __launch_bounds__(256) void loopattr_kernel(const int* __restrict__ row_ptr,
                                                       const int* __restrict__ csr_eid,
                                                       const float* __restrict__ ea,
                                                       float* __restrict__ la, int n) {
  int i = blockIdx.x * 256 + threadIdx.x;
  if (i >= n) return;
  int s = row_ptr[i], e = row_ptr[i + 1];
  float a[8] = {0, 0, 0, 0, 0, 0, 0, 0};
  for (int j = s; j < e; j++) {
    const float* p = ea + (size_t)csr_eid[j] * 8;
#pragma unroll
    for (int k = 0; k < 8; k++) a[k] += p[k];
  }
  float inv = 1.f / fmaxf((float)(e - s), 1.f);
  float* o = la + (size_t)i * 8;
#pragma unroll
  for (int k = 0; k < 8; k++) o[k] = a[k] * inv;
}

// ---------------------------------------------------------------- node transform GEMM
// out0 = x@w0 + b0, out1 = x@w1 + b1   (blockIdx.y picks 0/1)
// block = 256 threads, thread tile = 8 nodes x 4 cols.
template <int K, int NCOLS>
__global__ __launch_bounds__(256) void k1_kernel(const float* __restrict__ x,
                                                 const float* __restrict__ w0,
                                                 const float* __restrict__ b0,
                                                 float* __restrict__ out0,
                                                 const float* __restrict__ w1,
                                                 const float* __restrict__ b1,
                                                 float* __restrict__ out1, int n) {
  constexpr int KC = (K < 32) ? K : 32;
  constexpr int CG = NCOLS / 4;      // col groups
  constexpr int NG = 256 / CG;       // node groups
  constexpr int MTILE = NG * 8;
  constexpr int XS = KC + 4;         // padded LDS stride (16B-aligned)
  __shared__ float xs[MTILE * XS];
  __shared__ float ws[KC * NCOLS];

  const float* w = blockIdx.y ? w1 : w0;
  const float* b = blockIdx.y ? b1 : b0;
  float* out = blockIdx.y ? out1 : out0;

  int tid = threadIdx.x;
  int cg = tid % CG, ng = tid / CG;
  int c0 = 4 * cg, n0 = 8 * ng;
  int node0 = blockIdx.x * MTILE;

  float acc[8][4] = {};

  for (int k0 = 0; k0 < K; k0 += KC) {
    // stage x tile
    for (int idx = tid; idx < MTILE * KC / 4; idx += 256) {
      int nl = idx / (KC / 4), kq = idx % (KC / 4);
      int gn = node0 + nl;
      float4 v = make_float4(0.f, 0.f, 0.f, 0.f);
      if (gn < n) v = *(const float4*)&x[(size_t)gn * K + k0 + 4 * kq];
      *(float4*)&xs[nl * XS + 4 * kq] = v;
    }
    // stage w tile
    for (int idx = tid; idx < KC * NCOLS / 4; idx += 256) {
      int kr = idx / (NCOLS / 4), cq = idx % (NCOLS / 4);
      *(float4*)&ws[kr * NCOLS + 4 * cq] =
          *(const float4*)&w[(size_t)(k0 + kr) * NCOLS + 4 * cq];
    }
    __syncthreads();
#pragma unroll
    for (int kk = 0; kk < KC; kk += 4) {
      float4 wv0 = *(const float4*)&ws[(kk + 0) * NCOLS + c0];
      float4 wv1 = *(const float4*)&ws[(kk + 1) * NCOLS + c0];
      float4 wv2 = *(const float4*)&ws[(kk + 2) * NCOLS + c0];
      float4 wv3 = *(const float4*)&ws[(kk + 3) * NCOLS + c0];
#pragma unroll
      for (int j = 0; j < 8; j++) {
        float4 xv = *(const float4*)&xs[(n0 + j) * XS + kk];
        acc[j][0] += xv.x * wv0.x + xv.y * wv1.x + xv.z * wv2.x + xv.w * wv3.x;
        acc[j][1] += xv.x * wv0.y + xv.y * wv1.y + xv.z * wv2.y + xv.w * wv3.y;
        acc[j][2] += xv.x * wv0.z + xv.y * wv1.z + xv.z * wv2.z + xv.w * wv3.z;
        acc[j][3] += xv.x * wv0.w + xv.y * wv1.w + xv.z * wv2.w + xv.w * wv3.w;
      }
    }
    __syncthreads();
  }

  float4 bv = *(const float4*)&b[c0];
#pragma unroll
  for (int j = 0; j < 8; j++) {
    int gn = node0 + n0 + j;
    if (gn < n) {
      float4 o;
      o.x = acc[j][0] + bv.x;
      o.y = acc[j][1] + bv.y;
      o.z = acc[j][2] + bv.z;
      o.w = acc[j][3] + bv.w;
      *(float4*)&out[(size_t)gn * NCOLS + c0] = o;
    }
  }
}

// ---------------------------------------------------------------- fused GATv2 edge+softmax+aggregate
// One-pass softmax: out[dst] = (sum_e p_e * xl[src_e]) / (sum_e p_e + 1e-16),
// p_e = exp(logit_e) (no max-shift needed, logits are O(1..10)).
// 8 lanes per head, 4 channels per lane. H in {4 (HC=128), 1 (HC=32)}.
template <int H>
__global__ __launch_bounds__(128) void k2_kernel(
    const float* __restrict__ xl, const float* __restrict__ xr,
    const int* __restrict__ row_ptr, const int* __restrict__ csr_src,
    const int* __restrict__ csr_eid, const float* __restrict__ edge_attr,
    const float* __restrict__ loop_attr, const float* __restrict__ we,
    const float* __restrict__ att, const float* __restrict__ bc,
    float* __restrict__ out, int n) {
  constexpr int HC = H * 32;
  constexpr int NL = HC / 4;   // lanes per node (32 or 8)
  constexpr int NPB = 128 / NL;

  int tid = threadIdx.x;
  int ln = tid / NL, q = tid % NL;
  int c0 = 4 * q;
  int node = blockIdx.x * NPB + ln;
  if (node >= n) return;

  // per-thread slice of we (8 x 4) and att (4)
  float wreg[8][4];
#pragma unroll
  for (int k = 0; k < 8; k++) {
    float4 v = *(const float4*)&we[k * HC + c0];
    wreg[k][0] = v.x; wreg[k][1] = v.y; wreg[k][2] = v.z; wreg[k][3] = v.w;
  }
  float4 av = *(const float4*)&att[c0];
  float atr[4] = {av.x, av.y, av.z, av.w};
  float4 xv = *(const float4*)&xr[(size_t)node * HC + c0];
  float xrr[4] = {xv.x, xv.y, xv.z, xv.w};

  float acc[4] = {0.f, 0.f, 0.f, 0.f};
  float s = 0.f;

  int start = row_ptr[node], end = row_ptr[node + 1];
  for (int j = start; j <= end; j++) {   // j == end -> self loop
    int src;
    const float* ep;
    if (j < end) {
      src = csr_src[j];
      ep = edge_attr + (size_t)csr_eid[j] * 8;
    } else {
      src = node;
      ep = loop_attr + (size_t)node * 8;
    }
    float4 e0 = *(const float4*)ep;
    float4 e1 = *(const float4*)(ep + 4);
    float ev[8] = {e0.x, e0.y, e0.z, e0.w, e1.x, e1.y, e1.z, e1.w};
    float4 xlv4 = *(const float4*)&xl[(size_t)src * HC + c0];
    float xlv[4] = {xlv4.x, xlv4.y, xlv4.z, xlv4.w};

    float part = 0.f;
#pragma unroll
    for (int i = 0; i < 4; i++) {
      float t = xlv[i] + xrr[i];
#pragma unroll
      for (int k = 0; k < 8; k++) t += ev[k] * wreg[k][i];
      t = fmaxf(t, 0.2f * t);        // leaky_relu(t, 0.2)
      part += t * atr[i];
    }
    // reduce across the 8 lanes of this head (8-aligned groups)
    part += __shfl_xor(part, 1, 64);
    part += __shfl_xor(part, 2, 64);
    part += __shfl_xor(part, 4, 64);
    float p = __expf(part);
    s += p;
#pragma unroll
    for (int i = 0; i < 4; i++) acc[i] += p * xlv[i];
  }

  float inv = 1.f / (s + 1e-16f);
  float4 o;
  float ov[4];
#pragma unroll
  for (int i = 0; i < 4; i++) {
    float v = acc[i] * inv + bc[c0 + i];
    ov[i] = v > 0.f ? v : (__expf(v) - 1.f);   // elu
  }
  o.x = ov[0]; o.y = ov[1]; o.z = ov[2]; o.w = ov[3];
  *(float4*)&out[(size_t)node * HC + c0] = o;
}

// ---------------------------------------------------------------- pooling + MLP

__global__ __launch_bounds__(256) void pool_kernel(const float* __restrict__ h,
                                                   const int* __restrict__ batch,
                                                   float* __restrict__ gsum,
                                                   int* __restrict__ gcnt, int n) {
  long long idx = (long long)blockIdx.x * 256 + threadIdx.x;
  if (idx >= (long long)n * 32) return;
  int node = (int)(idx >> 5);
  int c = (int)(idx & 31);
  int g = batch[node];
  atomicAdd(&gsum[g * 32 + c], h[(size_t)node * 32 + c]);
  if (c == 0) atomicAdd(&gcnt[g], 1);
}

__global__ __launch_bounds__(64) void fc_kernel(const float* __restrict__ gsum,
                                                const int* __restrict__ gcnt,
                                                const float* __restrict__ w1,
                                                const float* __restrict__ b1,
                                                const float* __restrict__ w2,
                                                const float* __restrict__ b2,
                                                float* __restrict__ out) {
  __shared__ float g[32];
  __shared__ float a1[64];
  int gi = blockIdx.x;
  int t = threadIdx.x;
  if (t < 32) {
    float c = (float)gcnt[gi];
    g[t] = gsum[gi * 32 + t] / fmaxf(c, 1.f);
  }
  __syncthreads();
  float v = b1[t];
  for (int k = 0; k < 32; k++) v += g[k] * w1[k * 64 + t];
  a1[t] = v > 0.f ? v : (__expf(v) - 1.f);
  __syncthreads();
  if (t < 4) {
    float o = b2[t];
    for (int k = 0; k < 64; k++) o += a1[k] * w2[k * 4 + t];
    out[gi * 4 + t] = o;
  }
}

// ---------------------------------------------------------------- launch

extern "C" void kernel_launch(void* const* d_in, const int* in_sizes, int n_in,
                              void* d_out, int out_size, void* d_ws, size_t ws_size,
                              hipStream_t stream) {
  const float* x     = (const float*)d_in[0];
  const int*   ei    = (const int*)d_in[1];
  const float* eattr = (const float*)d_in[2];
  const int*   batch = (const int*)d_in[3];
  const float *wl1 = (const float*)d_in[4],  *bl1 = (const float*)d_in[5];
  const float *wr1 = (const float*)d_in[6],  *br1 = (const float*)d_in[7];
  const float *we1 = (const float*)d_in[8],  *at1 = (const float*)d_in[9];
  const float *bc1 = (const float*)d_in[10];
  const float *wl2 = (const float*)d_in[11], *bl2 = (const float*)d_in[12];
  const float *wr2 = (const float*)d_in[13], *br2 = (const float*)d_in[14];
  const float *we2 = (const float*)d_in[15], *at2 = (const float*)d_in[16];
  const float *bc2 = (const float*)d_in[17];
  const float *wl3 = (const float*)d_in[18], *bl3 = (const float*)d_in[19];
  const float *wr3 = (const float*)d_in[20], *br3 = (const float*)d_in[21];
  const float *we3 = (const float*)d_in[22], *at3 = (const float*)d_in[23];
  const float *bc3 = (const float*)d_in[24];
  const float *wf1 = (const float*)d_in[25], *bf1 = (const float*)d_in[26];
  const float *wf2 = (const float*)d_in[27], *bf2 = (const float*)d_in[28];

  int N = in_sizes[0] / 16;
  int E = in_sizes[1] / 2;
  const int* srcp = ei;
  const int* dstp = ei + E;

  char* wsb = (char*)d_ws;
  size_t off = 0;
  auto alloc = [&](size_t bytes) -> char* {
    char* p = wsb + off;
    off += (bytes + 255) & ~(size_t)255;
    return p;
  };
  int*   cnt     = (int*)alloc((size_t)N * 4);
  int*   row_ptr = (int*)alloc((size_t)(N + 1) * 4);
  int*   fill    = (int*)alloc((size_t)N * 4);
  int*   csr_src = (int*)alloc((size_t)E * 4);
  int*   csr_eid = (int*)alloc((size_t)E * 4);
  float* la      = (float*)alloc((size_t)N * 8 * 4);
  float* xl      = (float*)alloc((size_t)N * 128 * 4);
  float* xr      = (float*)alloc((size_t)N * 128 * 4);
  float* h       = (float*)alloc((size_t)N * 128 * 4);
  float* gsum    = (float*)alloc((size_t)GNUM * 32 * 4);
  int*   gcnt    = (int*)alloc((size_t)GNUM * 4);

  hipMemsetAsync(cnt, 0, (size_t)N * 4, stream);
  hipMemsetAsync(gsum, 0, (size_t)GNUM * 32 * 4, stream);
  hipMemsetAsync(gcnt, 0, (size_t)GNUM * 4, stream);

  hist_kernel<<<(E + 255) / 256, 256, 0, stream>>>(dstp, cnt, E);
  scan_kernel<<<1, 1024, 0, stream>>>(cnt, row_ptr, fill, N);
  scatter_kernel<<<(E + 255) / 256, 256, 0, stream>>>(srcp, dstp, fill, csr_src, csr_eid, E);
  loopattr_kernel<<<(N + 255) / 256, 256, 0, stream>>>(row_ptr, csr_eid, eattr, la, N);

  // layer 1: K=16 -> 128
  k1_kernel<16, 128><<<dim3((N + 63) / 64, 2), 256, 0, stream>>>(x, wl1, bl1, xl, wr1, br1, xr, N);
  k2_kernel<4><<<(N + 3) / 4, 128, 0, stream>>>(xl, xr, row_ptr, csr_src, csr_eid, eattr, la,
                                                we1, at1, bc1, h, N);
  // layer 2: K=128 -> 128
  k1_kernel<128, 128><<<dim3((N + 63) / 64, 2), 256, 0, stream>>>(h, wl2, bl2, xl, wr2, br2, xr, N);
  k2_kernel<4><<<(N + 3) / 4, 128, 0, stream>>>(xl, xr, row_ptr, csr_src, csr_eid, eattr, la,
                                                we2, at2, bc2, h, N);
  // layer 3: K=128 -> 32 (single head)
  k1_kernel<128, 32><<<dim3((N + 255) / 256, 2), 256, 0, stream>>>(h, wl3, bl3, xl, wr3, br3, xr, N);
  k2_kernel<1><<<(N + 15) / 16, 128, 0, stream>>>(xl, xr, row_ptr, csr_src, csr_eid, eattr, la,
                                                  we3, at3, bc3, h, N);

  pool_kernel<<<(int)(((long long)N * 32 + 255) / 256), 256, 0, stream>>>(h, batch, gsum, gcnt, N);
  fc_kernel<<<GNUM, 64, 0, stream>>>(gsum, gcnt, wf1, bf1, wf2, bf2, (float*)d_out);
}

// Round 2
// 1527.913 us; speedup vs baseline: 1.3099x; 1.3099x over previous
//
#include <hip/hip_runtime.h>
#include <cstdint>

// GNN GATv2 x3 + mean-pool + MLP.  f32 throughout.
constexpr int GNUM = 128;   // graphs
// IN=16, HID=32, HEADS=4, EDIM=8, OUT=4, HC=128

// ---------------------------------------------------------------- setup kernels

__global__ __launch_bounds__(256) void hist_kernel(const int* __restrict__ dst,
                                                   int* __restrict__ cnt, int E) {
  int i = blockIdx.x * 256 + threadIdx.x;
  if (i < E) atomicAdd(&cnt[dst[i]], 1);
}

__global__ __launch_bounds__(1024) void scan_kernel(const int* __restrict__ cnt,
                                                    int* __restrict__ row_ptr,
                                                    int* __restrict__ fill, int n) {
  __shared__ int part[1024];
  int t = threadIdx.x;
  int chunk = (n + 1023) / 1024;
  int lo = t * chunk;
  if (lo > n) lo = n;
  int hi = lo + chunk;
  if (hi > n) hi = n;
  int s = 0;
  for (int i = lo; i < hi; i++) s += cnt[i];
  part[t] = s;
  __syncthreads();
  for (int off = 1; off < 1024; off <<= 1) {
    int v = (t >= off) ? part[t - off] : 0;
    __syncthreads();
    part[t] += v;
    __syncthreads();
  }
  int run = (t == 0) ? 0 : part[t - 1];
  for (int i = lo; i < hi; i++) {
    row_ptr[i] = run;
    fill[i] = run;
    run += cnt[i];
  }
  if (t == 0) row_ptr[n] = part[1023];
}

__global__ __launch_bounds__(256) void scatter_kernel(const int* __restrict__ src,
                                                      const int* __restrict__ dst,
                                                      int* __restrict__ fill,
                                                      int* __restrict__ csr_src,
                                                      int* __restrict__ csr_eid, int E) {
  int i = blockIdx.x * 256 + threadIdx.x;
  if (i >= E) return;
  int d = dst[i];
  int p = atomicAdd(&fill[d], 1);
  csr_src[p] = src[i];
  csr_eid[p] = i;
}

// loop_attr[i] = mean of incoming edge_attr (fill_value='mean'), 0 if no in-edges
__global__ __launch_bounds__(256) void loopattr_kernel(const int* __restrict__ row_ptr,
                                                       const int* __restrict__ csr_eid,
                                                       const float* __restrict__ ea,
                                                       float* __restrict__ la, int n) {
  int i = blockIdx.x * 256 + threadIdx.x;
  if (i >= n) return;
  int s = row_ptr[i], e = row_ptr[i + 1];
  float a[8] = {0, 0, 0, 0, 0, 0, 0, 0};
  for (int j = s; j < e; j++) {
    const float* p = ea + (size_t)csr_eid[j] * 8;
#pragma unroll
    for (int k = 0; k < 8; k++) a[k] += p[k];
  }
  float inv = 1.f / fmaxf((float)(e - s), 1.f);
  float* o = la + (size_t)i * 8;
#pragma unroll
  for (int k = 0; k < 8; k++) o[k] = a[k] * inv;
}

// ---------------------------------------------------------------- node transform GEMM
template <int K, int NCOLS>
__global__ __launch_bounds__(256) void k1_kernel(const float* __restrict__ x,
                                                 const float* __restrict__ w0,
                                                 const float* __restrict__ b0,
                                                 float* __restrict__ out0,
                                                 const float* __restrict__ w1,
                                                 const float* __restrict__ b1,
                                                 float* __restrict__ out1, int n) {
  constexpr int KC = (K < 32) ? K : 32;
  constexpr int CG = NCOLS / 4;      // col groups
  constexpr int NG = 256 / CG;       // node groups
  constexpr int MTILE = NG * 8;
  constexpr int XS = KC + 4;         // padded LDS stride (16B-aligned)
  __shared__ float xs[MTILE * XS];
  __shared__ float ws[KC * NCOLS];

  const float* w = blockIdx.y ? w1 : w0;
  const float* b = blockIdx.y ? b1 : b0;
  float* out = blockIdx.y ? out1 : out0;

  int tid = threadIdx.x;
  int cg = tid % CG, ng = tid / CG;
  int c0 = 4 * cg, n0 = 8 * ng;
  int node0 = blockIdx.x * MTILE;

  float acc[8][4] = {};

  for (int k0 = 0; k0 < K; k0 += KC) {
    // stage x tile
    for (int idx = tid; idx < MTILE * KC / 4; idx += 256) {
      int nl = idx / (KC / 4), kq = idx % (KC / 4);
      int gn = node0 + nl;
      float4 v = make_float4(0.f, 0.f, 0.f, 0.f);
      if (gn < n) v = *(const float4*)&x[(size_t)gn * K + k0 + 4 * kq];
      *(float4*)&xs[nl * XS + 4 * kq] = v;
    }
    // stage w tile
    for (int idx = tid; idx < KC * NCOLS / 4; idx += 256) {
      int kr = idx / (NCOLS / 4), cq = idx % (NCOLS / 4);
      *(float4*)&ws[kr * NCOLS + 4 * cq] =
          *(const float4*)&w[(size_t)(k0 + kr) * NCOLS + 4 * cq];
    }
    __syncthreads();
#pragma unroll
    for (int kk = 0; kk < KC; kk += 4) {
      float4 wv0 = *(const float4*)&ws[(kk + 0) * NCOLS + c0];
      float4 wv1 = *(const float4*)&ws[(kk + 1) * NCOLS + c0];
      float4 wv2 = *(const float4*)&ws[(kk + 2) * NCOLS + c0];
      float4 wv3 = *(const float4*)&ws[(kk + 3) * NCOLS + c0];
#pragma unroll
      for (int j = 0; j < 8; j++) {
        float4 xv = *(const float4*)&xs[(n0 + j) * XS + kk];
        acc[j][0] += xv.x * wv0.x + xv.y * wv1.x + xv.z * wv2.x + xv.w * wv3.x;
        acc[j][1] += xv.x * wv0.y + xv.y * wv1.y + xv.z * wv2.y + xv.w * wv3.y;
        acc[j][2] += xv.x * wv0.z + xv.y * wv1.z + xv.z * wv2.z + xv.w * wv3.z;
        acc[j][3] += xv.x * wv0.w + xv.y * wv1.w + xv.z * wv2.w + xv.w * wv3.w;
      }
    }
    __syncthreads();
  }

  float4 bv = *(const float4*)&b[c0];
#pragma unroll
  for (int j = 0; j < 8; j++) {
    int gn = node0 + n0 + j;
    if (gn < n) {
      float4 o;
      o.x = acc[j][0] + bv.x;
      o.y = acc[j][1] + bv.y;
      o.z = acc[j][2] + bv.z;
      o.w = acc[j][3] + bv.w;
      *(float4*)&out[(size_t)gn * NCOLS + c0] = o;
    }
  }
}

// ---------------------------------------------------------------- fused GATv2 edge+softmax+aggregate
template <int H>
__global__ __launch_bounds__(128) void k2_kernel(
    const float* __restrict__ xl, const float* __restrict__ xr,
    const int* __restrict__ row_ptr, const int* __restrict__ csr_src,
    const int* __restrict__ csr_eid, const float* __restrict__ edge_attr,
    const float* __restrict__ loop_attr, const float* __restrict__ we,
    const float* __restrict__ att, const float* __restrict__ bc,
    float* __restrict__ out, int n) {
  constexpr int HC = H * 32;
  constexpr int NL = HC / 4;   // lanes per node (32 or 8)
  constexpr int NPB = 128 / NL;

  int tid = threadIdx.x;
  int ln = tid / NL, q = tid % NL;
  int c0 = 4 * q;
  int node = blockIdx.x * NPB + ln;
  if (node >= n) return;

  float wreg[8][4];
#pragma unroll
  for (int k = 0; k < 8; k++) {
    float4 v = *(const float4*)&we[k * HC + c0];
    wreg[k][0] = v.x; wreg[k][1] = v.y; wreg[k][2] = v.z; wreg[k][3] = v.w;
  }
  float4 av = *(const float4*)&att[c0];
  float atr[4] = {av.x, av.y, av.z, av.w};
  float4 xv = *(const float4*)&xr[(size_t)node * HC + c0];
  float xrr[4] = {xv.x, xv.y, xv.z, xv.w};

  float acc[4] = {0.f, 0.f, 0.f, 0.f};
  float s = 0.f;

  int start = row_ptr[node], end = row_ptr[node + 1];
  for (int j = start; j <= end; j++) {   // j == end -> self loop
    int src;
    const float* ep;
    if (j < end) {
      src = csr_src[j];
      ep = edge_attr + (size_t)csr_eid[j] * 8;
    } else {
      src = node;
      ep = loop_attr + (size_t)node * 8;
    }
    float4 e0 = *(const float4*)ep;
    float4 e1 = *(const float4*)(ep + 4);
    float ev[8] = {e0.x, e0.y, e0.z, e0.w, e1.x, e1.y, e1.z, e1.w};
    float4 xlv4 = *(const float4*)&xl[(size_t)src * HC + c0];
    float xlv[4] = {xlv4.x, xlv4.y, xlv4.z, xlv4.w};

    float part = 0.f;
#pragma unroll
    for (int i = 0; i < 4; i++) {
      float t = xlv[i] + xrr[i];
#pragma unroll
      for (int k = 0; k < 8; k++) t += ev[k] * wreg[k][i];
      t = fmaxf(t, 0.2f * t);        // leaky_relu(t, 0.2)
      part += t * atr[i];
    }
    part += __shfl_xor(part, 1, 64);
    part += __shfl_xor(part, 2, 64);
    part += __shfl_xor(part, 4, 64);
    float p = __expf(part);
    s += p;
#pragma unroll
    for (int i = 0; i < 4; i++) acc[i] += p * xlv[i];
  }

  float inv = 1.f / (s + 1e-16f);
  float4 o;
  float ov[4];
#pragma unroll
  for (int i = 0; i < 4; i++) {
    float v = acc[i] * inv + bc[c0 + i];
    ov[i] = v > 0.f ? v : (__expf(v) - 1.f);   // elu
  }
  o.x = ov[0]; o.y = ov[1]; o.z = ov[2]; o.w = ov[3];
  *(float4*)&out[(size_t)node * HC + c0] = o;
}

// ---------------------------------------------------------------- pooling + MLP
// batch is SORTED -> each graph is a contiguous node range. Find boundaries by
// binary search (robust to empty graphs), then deterministic block reduction.

__global__ __launch_bounds__(256) void gbound_kernel(const int* __restrict__ batch,
                                                     int* __restrict__ gstart, int n) {
  int g = blockIdx.x * 256 + threadIdx.x;
  if (g > GNUM) return;
  int lo = 0, hi = n;
  while (lo < hi) {
    int mid = (lo + hi) >> 1;
    if (batch[mid] < g) lo = mid + 1; else hi = mid;
  }
  gstart[g] = lo;
}

// one block per graph; 256 threads = 8 rows x 32 channels per iteration
__global__ __launch_bounds__(256) void pool2_kernel(const float* __restrict__ h,
                                                    const int* __restrict__ gstart,
                                                    float* __restrict__ gmean) {
  __shared__ float red[256];
  int g = blockIdx.x;
  int t = threadIdx.x;
  int s = gstart[g], e = gstart[g + 1];
  int c = t & 31, rg = t >> 5;
  float acc = 0.f;
  for (int i = s + rg; i < e; i += 8) acc += h[(size_t)i * 32 + c];
  red[t] = acc;
  __syncthreads();
  if (t < 128) red[t] += red[t + 128];
  __syncthreads();
  if (t < 64) red[t] += red[t + 64];
  __syncthreads();
  if (t < 32) {
    float v = red[t] + red[t + 32];
    gmean[g * 32 + t] = v / fmaxf((float)(e - s), 1.f);
  }
}

__global__ __launch_bounds__(64) void fc_kernel(const float* __restrict__ gmean,
                                                const float* __restrict__ w1,
                                                const float* __restrict__ b1,
                                                const float* __restrict__ w2,
                                                const float* __restrict__ b2,
                                                float* __restrict__ out) {
  __shared__ float g[32];
  __shared__ float a1[64];
  int gi = blockIdx.x;
  int t = threadIdx.x;
  if (t < 32) g[t] = gmean[gi * 32 + t];
  __syncthreads();
  float v = b1[t];
  for (int k = 0; k < 32; k++) v += g[k] * w1[k * 64 + t];
  a1[t] = v > 0.f ? v : (__expf(v) - 1.f);
  __syncthreads();
  if (t < 4) {
    float o = b2[t];
    for (int k = 0; k < 64; k++) o += a1[k] * w2[k * 4 + t];
    out[gi * 4 + t] = o;
  }
}

// ---------------------------------------------------------------- launch

extern "C" void kernel_launch(void* const* d_in, const int* in_sizes, int n_in,
                              void* d_out, int out_size, void* d_ws, size_t ws_size,
                              hipStream_t stream) {
  const float* x     = (const float*)d_in[0];
  const int*   ei    = (const int*)d_in[1];
  const float* eattr = (const float*)d_in[2];
  const int*   batch = (const int*)d_in[3];
  const float *wl1 = (const float*)d_in[4],  *bl1 = (const float*)d_in[5];
  const float *wr1 = (const float*)d_in[6],  *br1 = (const float*)d_in[7];
  const float *we1 = (const float*)d_in[8],  *at1 = (const float*)d_in[9];
  const float *bc1 = (const float*)d_in[10];
  const float *wl2 = (const float*)d_in[11], *bl2 = (const float*)d_in[12];
  const float *wr2 = (const float*)d_in[13], *br2 = (const float*)d_in[14];
  const float *we2 = (const float*)d_in[15], *at2 = (const float*)d_in[16];
  const float *bc2 = (const float*)d_in[17];
  const float *wl3 = (const float*)d_in[18], *bl3 = (const float*)d_in[19];
  const float *wr3 = (const float*)d_in[20], *br3 = (const float*)d_in[21];
  const float *we3 = (const float*)d_in[22], *at3 = (const float*)d_in[23];
  const float *bc3 = (const float*)d_in[24];
  const float *wf1 = (const float*)d_in[25], *bf1 = (const float*)d_in[26];
  const float *wf2 = (const float*)d_in[27], *bf2 = (const float*)d_in[28];

  int N = in_sizes[0] / 16;
  int E = in_sizes[1] / 2;
  const int* srcp = ei;
  const int* dstp = ei + E;

  char* wsb = (char*)d_ws;
  size_t off = 0;
  auto alloc = [&](size_t bytes) -> char* {
    char* p = wsb + off;
    off += (bytes + 255) & ~(size_t)255;
    return p;
  };
  int*   cnt     = (int*)alloc((size_t)N * 4);
  int*   row_ptr = (int*)alloc((size_t)(N + 1) * 4);
  int*   fill    = (int*)alloc((size_t)N * 4);
  int*   csr_src = (int*)alloc((size_t)E * 4);
  int*   csr_eid = (int*)alloc((size_t)E * 4);
  float* la      = (float*)alloc((size_t)N * 8 * 4);
  float* xl      = (float*)alloc((size_t)N * 128 * 4);
  float* xr      = (float*)alloc((size_t)N * 128 * 4);
  float* h       = (float*)alloc((size_t)N * 128 * 4);
  float* gmean   = (float*)alloc((size_t)GNUM * 32 * 4);
  int*   gstart  = (int*)alloc((size_t)(GNUM + 1) * 4);

  hipMemsetAsync(cnt, 0, (size_t)N * 4, stream);

  hist_kernel<<<(E + 255) / 256, 256, 0, stream>>>(dstp, cnt, E);
  scan_kernel<<<1, 1024, 0, stream>>>(cnt, row_ptr, fill, N);
  scatter_kernel<<<(E + 255) / 256, 256, 0, stream>>>(srcp, dstp, fill, csr_src, csr_eid, E);
  loopattr_kernel<<<(N + 255) / 256, 256, 0, stream>>>(row_ptr, csr_eid, eattr, la, N);
  gbound_kernel<<<1, 256, 0, stream>>>(batch, gstart, N);

  // layer 1: K=16 -> 128
  k1_kernel<16, 128><<<dim3((N + 63) / 64, 2), 256, 0, stream>>>(x, wl1, bl1, xl, wr1, br1, xr, N);
  k2_kernel<4><<<(N + 3) / 4, 128, 0, stream>>>(xl, xr, row_ptr, csr_src, csr_eid, eattr, la,
                                                we1, at1, bc1, h, N);
  // layer 2: K=128 -> 128
  k1_kernel<128, 128><<<dim3((N + 63) / 64, 2), 256, 0, stream>>>(h, wl2, bl2, xl, wr2, br2, xr, N);
  k2_kernel<4><<<(N + 3) / 4, 128, 0, stream>>>(xl, xr, row_ptr, csr_src, csr_eid, eattr, la,
                                                we2, at2, bc2, h, N);
  // layer 3: K=128 -> 32 (single head)
  k1_kernel<128, 32><<<dim3((N + 255) / 256, 2), 256, 0, stream>>>(h, wl3, bl3, xl, wr3, br3, xr, N);
  k2_kernel<1><<<(N + 15) / 16, 128, 0, stream>>>(xl, xr, row_ptr, csr_src, csr_eid, eattr, la,
                                                  we3, at3, bc3, h, N);

  pool2_kernel<<<GNUM, 256, 0, stream>>>(h, gstart, gmean);
  fc_kernel<<<GNUM, 64, 0, stream>>>(gmean, wf1, bf1, wf2, bf2, (float*)d_out);
}

// Round 3
// 1315.710 us; speedup vs baseline: 1.5212x; 1.1613x over previous
//
#include <hip/hip_runtime.h>
#include <cstdint>
#include <type_traits>

// GNN GATv2 x3 + mean-pool + MLP.
// f32 GEMMs; fp16 feature tables (xl/xr) + fp16 CSR-ordered edge features for
// the gather-heavy attention kernels. Self-loop inlined as last CSR entry.
constexpr int GNUM = 128;   // graphs

typedef _Float16 h4 __attribute__((ext_vector_type(4)));
typedef _Float16 h8 __attribute__((ext_vector_type(8)));

// ---------------------------------------------------------------- setup kernels

__global__ __launch_bounds__(256) void hist_kernel(const int* __restrict__ dst,
                                                   int* __restrict__ cnt, int E) {
  int i = blockIdx.x * 256 + threadIdx.x;
  if (i < E) atomicAdd(&cnt[dst[i]], 1);
}

// exclusive scan of (cnt[i]+1): CSR with one extra self-loop slot per node
__global__ __launch_bounds__(1024) void scan_kernel(const int* __restrict__ cnt,
                                                    int* __restrict__ row_ptr,
                                                    int* __restrict__ fill, int n) {
  __shared__ int part[1024];
  int t = threadIdx.x;
  int chunk = (n + 1023) / 1024;
  int lo = t * chunk;
  if (lo > n) lo = n;
  int hi = lo + chunk;
  if (hi > n) hi = n;
  int s = 0;
  for (int i = lo; i < hi; i++) s += cnt[i] + 1;
  part[t] = s;
  __syncthreads();
  for (int off = 1; off < 1024; off <<= 1) {
    int v = (t >= off) ? part[t - off] : 0;
    __syncthreads();
    part[t] += v;
    __syncthreads();
  }
  int run = (t == 0) ? 0 : part[t - 1];
  for (int i = lo; i < hi; i++) {
    row_ptr[i] = run;
    fill[i] = run;
    run += cnt[i] + 1;
  }
  if (t == 0) row_ptr[n] = part[1023];
}

// scatter edges into CSR slots; write fp16 edge features directly in CSR order
__global__ __launch_bounds__(256) void scatter_kernel(const int* __restrict__ src,
                                                      const int* __restrict__ dst,
                                                      const float* __restrict__ ea,
                                                      int* __restrict__ fill,
                                                      int* __restrict__ csr_src,
                                                      _Float16* __restrict__ ea_csr, int E) {
  int i = blockIdx.x * 256 + threadIdx.x;
  if (i >= E) return;
  int d = dst[i];
  int p = atomicAdd(&fill[d], 1);
  csr_src[p] = src[i];
  float4 e0 = *(const float4*)&ea[(size_t)i * 8];
  float4 e1 = *(const float4*)&ea[(size_t)i * 8 + 4];
  h8 v;
  v[0] = (_Float16)e0.x; v[1] = (_Float16)e0.y; v[2] = (_Float16)e0.z; v[3] = (_Float16)e0.w;
  v[4] = (_Float16)e1.x; v[5] = (_Float16)e1.y; v[6] = (_Float16)e1.z; v[7] = (_Float16)e1.w;
  *(h8*)&ea_csr[(size_t)p * 8] = v;
}

// fill the self-loop slot (last of each segment): src=i, feature=mean of segment
__global__ __launch_bounds__(256) void selfloop_kernel(const int* __restrict__ row_ptr,
                                                       int* __restrict__ csr_src,
                                                       _Float16* __restrict__ ea_csr, int n) {
  int i = blockIdx.x * 256 + threadIdx.x;
  if (i >= n) return;
  int s = row_ptr[i], e = row_ptr[i + 1] - 1;   // [s,e) = real edges, e = self slot
  float a[8] = {0, 0, 0, 0, 0, 0, 0, 0};
  for (int j = s; j < e; j++) {
    h8 t = *(const h8*)&ea_csr[(size_t)j * 8];
#pragma unroll
    for (int k = 0; k < 8; k++) a[k] += (float)t[k];
  }
  float inv = 1.f / fmaxf((float)(e - s), 1.f);
  h8 o;
#pragma unroll
  for (int k = 0; k < 8; k++) o[k] = (_Float16)(a[k] * inv);
  *(h8*)&ea_csr[(size_t)e * 8] = o;
  csr_src[e] = i;
}

// ---------------------------------------------------------------- node transform GEMM
// out0 = x@w0 + b0, out1 = x@w1 + b1 (blockIdx.y picks). OT = float or _Float16.
template <int K, int NCOLS, typename OT>
__global__ __launch_bounds__(256) void k1_kernel(const float* __restrict__ x,
                                                 const float* __restrict__ w0,
                                                 const float* __restrict__ b0,
                                                 OT* __restrict__ out0,
                                                 const float* __restrict__ w1,
                                                 const float* __restrict__ b1,
                                                 OT* __restrict__ out1, int n) {
  constexpr int KC = (K < 32) ? K : 32;
  constexpr int CG = NCOLS / 4;      // col groups
  constexpr int NG = 256 / CG;       // node groups
  constexpr int MTILE = NG * 8;
  constexpr int XS = KC + 4;
  __shared__ float xs[MTILE * XS];
  __shared__ float ws[KC * NCOLS];

  const float* w = blockIdx.y ? w1 : w0;
  const float* b = blockIdx.y ? b1 : b0;
  OT* out = blockIdx.y ? out1 : out0;

  int tid = threadIdx.x;
  int cg = tid % CG, ng = tid / CG;
  int c0 = 4 * cg, n0 = 8 * ng;
  int node0 = blockIdx.x * MTILE;

  float acc[8][4] = {};

  for (int k0 = 0; k0 < K; k0 += KC) {
    for (int idx = tid; idx < MTILE * KC / 4; idx += 256) {
      int nl = idx / (KC / 4), kq = idx % (KC / 4);
      int gn = node0 + nl;
      float4 v = make_float4(0.f, 0.f, 0.f, 0.f);
      if (gn < n) v = *(const float4*)&x[(size_t)gn * K + k0 + 4 * kq];
      *(float4*)&xs[nl * XS + 4 * kq] = v;
    }
    for (int idx = tid; idx < KC * NCOLS / 4; idx += 256) {
      int kr = idx / (NCOLS / 4), cq = idx % (NCOLS / 4);
      *(float4*)&ws[kr * NCOLS + 4 * cq] =
          *(const float4*)&w[(size_t)(k0 + kr) * NCOLS + 4 * cq];
    }
    __syncthreads();
#pragma unroll
    for (int kk = 0; kk < KC; kk += 4) {
      float4 wv0 = *(const float4*)&ws[(kk + 0) * NCOLS + c0];
      float4 wv1 = *(const float4*)&ws[(kk + 1) * NCOLS + c0];
      float4 wv2 = *(const float4*)&ws[(kk + 2) * NCOLS + c0];
      float4 wv3 = *(const float4*)&ws[(kk + 3) * NCOLS + c0];
#pragma unroll
      for (int j = 0; j < 8; j++) {
        float4 xv = *(const float4*)&xs[(n0 + j) * XS + kk];
        acc[j][0] += xv.x * wv0.x + xv.y * wv1.x + xv.z * wv2.x + xv.w * wv3.x;
        acc[j][1] += xv.x * wv0.y + xv.y * wv1.y + xv.z * wv2.y + xv.w * wv3.y;
        acc[j][2] += xv.x * wv0.z + xv.y * wv1.z + xv.z * wv2.z + xv.w * wv3.z;
        acc[j][3] += xv.x * wv0.w + xv.y * wv1.w + xv.z * wv2.w + xv.w * wv3.w;
      }
    }
    __syncthreads();
  }

  float4 bv = *(const float4*)&b[c0];
#pragma unroll
  for (int j = 0; j < 8; j++) {
    int gn = node0 + n0 + j;
    if (gn < n) {
      if constexpr (std::is_same_v<OT, float>) {
        float4 o;
        o.x = acc[j][0] + bv.x; o.y = acc[j][1] + bv.y;
        o.z = acc[j][2] + bv.z; o.w = acc[j][3] + bv.w;
        *(float4*)&out[(size_t)gn * NCOLS + c0] = o;
      } else {
        h4 o;
        o[0] = (_Float16)(acc[j][0] + bv.x);
        o[1] = (_Float16)(acc[j][1] + bv.y);
        o[2] = (_Float16)(acc[j][2] + bv.z);
        o[3] = (_Float16)(acc[j][3] + bv.w);
        *(h4*)&out[(size_t)gn * NCOLS + c0] = o;
      }
    }
  }
}

// ---------------------------------------------------------------- fused GATv2 edge+softmax+aggregate
// One-pass softmax (no max-shift; logits O(1)). Self-loop is a normal CSR entry.
// 8 lanes per head, 4 channels per lane. H in {4 (HC=128), 1 (HC=32)}.
template <int H>
__global__ __launch_bounds__(128) void k2_kernel(
    const _Float16* __restrict__ xl, const _Float16* __restrict__ xr,
    const int* __restrict__ row_ptr, const int* __restrict__ csr_src,
    const _Float16* __restrict__ ea_csr, const float* __restrict__ we,
    const float* __restrict__ att, const float* __restrict__ bc,
    float* __restrict__ out, int n) {
  constexpr int HC = H * 32;
  constexpr int NL = HC / 4;   // lanes per node (32 or 8)
  constexpr int NPB = 128 / NL;

  int tid = threadIdx.x;
  int ln = tid / NL, q = tid % NL;
  int c0 = 4 * q;
  int node = blockIdx.x * NPB + ln;
  if (node >= n) return;

  float wreg[8][4];
#pragma unroll
  for (int k = 0; k < 8; k++) {
    float4 v = *(const float4*)&we[k * HC + c0];
    wreg[k][0] = v.x; wreg[k][1] = v.y; wreg[k][2] = v.z; wreg[k][3] = v.w;
  }
  float4 av = *(const float4*)&att[c0];
  float atr[4] = {av.x, av.y, av.z, av.w};
  h4 xrh = *(const h4*)&xr[(size_t)node * HC + c0];
  float xrr[4] = {(float)xrh[0], (float)xrh[1], (float)xrh[2], (float)xrh[3]};

  float acc[4] = {0.f, 0.f, 0.f, 0.f};
  float s = 0.f;

  int start = row_ptr[node], end = row_ptr[node + 1];
  for (int j = start; j < end; j++) {
    int src = csr_src[j];
    h8 eh = *(const h8*)&ea_csr[(size_t)j * 8];
    h4 xlh = *(const h4*)&xl[(size_t)src * HC + c0];
    float ev[8];
#pragma unroll
    for (int k = 0; k < 8; k++) ev[k] = (float)eh[k];
    float xlv[4] = {(float)xlh[0], (float)xlh[1], (float)xlh[2], (float)xlh[3]};

    float part = 0.f;
#pragma unroll
    for (int i = 0; i < 4; i++) {
      float t = xlv[i] + xrr[i];
#pragma unroll
      for (int k = 0; k < 8; k++) t += ev[k] * wreg[k][i];
      t = fmaxf(t, 0.2f * t);        // leaky_relu(t, 0.2)
      part += t * atr[i];
    }
    part += __shfl_xor(part, 1, 64);
    part += __shfl_xor(part, 2, 64);
    part += __shfl_xor(part, 4, 64);
    float p = __expf(part);
    s += p;
#pragma unroll
    for (int i = 0; i < 4; i++) acc[i] += p * xlv[i];
  }

  float inv = 1.f / (s + 1e-16f);
  float4 o;
  float ov[4];
#pragma unroll
  for (int i = 0; i < 4; i++) {
    float v = acc[i] * inv + bc[c0 + i];
    ov[i] = v > 0.f ? v : (__expf(v) - 1.f);   // elu
  }
  o.x = ov[0]; o.y = ov[1]; o.z = ov[2]; o.w = ov[3];
  *(float4*)&out[(size_t)node * HC + c0] = o;
}

// ---------------------------------------------------------------- pooling + MLP

__global__ __launch_bounds__(256) void gbound_kernel(const int* __restrict__ batch,
                                                     int* __restrict__ gstart, int n) {
  int g = blockIdx.x * 256 + threadIdx.x;
  if (g > GNUM) return;
  int lo = 0, hi = n;
  while (lo < hi) {
    int mid = (lo + hi) >> 1;
    if (batch[mid] < g) lo = mid + 1; else hi = mid;
  }
  gstart[g] = lo;
}

__global__ __launch_bounds__(256) void pool2_kernel(const float* __restrict__ h,
                                                    const int* __restrict__ gstart,
                                                    float* __restrict__ gmean) {
  __shared__ float red[256];
  int g = blockIdx.x;
  int t = threadIdx.x;
  int s = gstart[g], e = gstart[g + 1];
  int c = t & 31, rg = t >> 5;
  float acc = 0.f;
  for (int i = s + rg; i < e; i += 8) acc += h[(size_t)i * 32 + c];
  red[t] = acc;
  __syncthreads();
  if (t < 128) red[t] += red[t + 128];
  __syncthreads();
  if (t < 64) red[t] += red[t + 64];
  __syncthreads();
  if (t < 32) {
    float v = red[t] + red[t + 32];
    gmean[g * 32 + t] = v / fmaxf((float)(e - s), 1.f);
  }
}

__global__ __launch_bounds__(64) void fc_kernel(const float* __restrict__ gmean,
                                                const float* __restrict__ w1,
                                                const float* __restrict__ b1,
                                                const float* __restrict__ w2,
                                                const float* __restrict__ b2,
                                                float* __restrict__ out) {
  __shared__ float g[32];
  __shared__ float a1[64];
  int gi = blockIdx.x;
  int t = threadIdx.x;
  if (t < 32) g[t] = gmean[gi * 32 + t];
  __syncthreads();
  float v = b1[t];
  for (int k = 0; k < 32; k++) v += g[k] * w1[k * 64 + t];
  a1[t] = v > 0.f ? v : (__expf(v) - 1.f);
  __syncthreads();
  if (t < 4) {
    float o = b2[t];
    for (int k = 0; k < 64; k++) o += a1[k] * w2[k * 4 + t];
    out[gi * 4 + t] = o;
  }
}

// ---------------------------------------------------------------- launch

extern "C" void kernel_launch(void* const* d_in, const int* in_sizes, int n_in,
                              void* d_out, int out_size, void* d_ws, size_t ws_size,
                              hipStream_t stream) {
  const float* x     = (const float*)d_in[0];
  const int*   ei    = (const int*)d_in[1];
  const float* eattr = (const float*)d_in[2];
  const int*   batch = (const int*)d_in[3];
  const float *wl1 = (const float*)d_in[4],  *bl1 = (const float*)d_in[5];
  const float *wr1 = (const float*)d_in[6],  *br1 = (const float*)d_in[7];
  const float *we1 = (const float*)d_in[8],  *at1 = (const float*)d_in[9];
  const float *bc1 = (const float*)d_in[10];
  const float *wl2 = (const float*)d_in[11], *bl2 = (const float*)d_in[12];
  const float *wr2 = (const float*)d_in[13], *br2 = (const float*)d_in[14];
  const float *we2 = (const float*)d_in[15], *at2 = (const float*)d_in[16];
  const float *bc2 = (const float*)d_in[17];
  const float *wl3 = (const float*)d_in[18], *bl3 = (const float*)d_in[19];
  const float *wr3 = (const float*)d_in[20], *br3 = (const float*)d_in[21];
  const float *we3 = (const float*)d_in[22], *at3 = (const float*)d_in[23];
  const float *bc3 = (const float*)d_in[24];
  const float *wf1 = (const float*)d_in[25], *bf1 = (const float*)d_in[26];
  const float *wf2 = (const float*)d_in[27], *bf2 = (const float*)d_in[28];

  int N = in_sizes[0] / 16;
  int E = in_sizes[1] / 2;
  const int* srcp = ei;
  const int* dstp = ei + E;
  int EA = E + N;   // CSR entries incl. self-loops

  char* wsb = (char*)d_ws;
  size_t off = 0;
  auto alloc = [&](size_t bytes) -> char* {
    char* p = wsb + off;
    off += (bytes + 255) & ~(size_t)255;
    return p;
  };
  int*       cnt     = (int*)alloc((size_t)N * 4);
  int*       row_ptr = (int*)alloc((size_t)(N + 1) * 4);
  int*       fill    = (int*)alloc((size_t)N * 4);
  int*       csr_src = (int*)alloc((size_t)EA * 4);
  _Float16*  ea_csr  = (_Float16*)alloc((size_t)EA * 8 * 2);
  _Float16*  xl      = (_Float16*)alloc((size_t)N * 128 * 2);
  _Float16*  xr      = (_Float16*)alloc((size_t)N * 128 * 2);
  float*     h       = (float*)alloc((size_t)N * 128 * 4);
  float*     gmean   = (float*)alloc((size_t)GNUM * 32 * 4);
  int*       gstart  = (int*)alloc((size_t)(GNUM + 1) * 4);

  hipMemsetAsync(cnt, 0, (size_t)N * 4, stream);

  hist_kernel<<<(E + 255) / 256, 256, 0, stream>>>(dstp, cnt, E);
  scan_kernel<<<1, 1024, 0, stream>>>(cnt, row_ptr, fill, N);
  scatter_kernel<<<(E + 255) / 256, 256, 0, stream>>>(srcp, dstp, eattr, fill, csr_src, ea_csr, E);
  selfloop_kernel<<<(N + 255) / 256, 256, 0, stream>>>(row_ptr, csr_src, ea_csr, N);
  gbound_kernel<<<1, 256, 0, stream>>>(batch, gstart, N);

  // layer 1: K=16 -> 128
  k1_kernel<16, 128, _Float16><<<dim3((N + 63) / 64, 2), 256, 0, stream>>>(
      x, wl1, bl1, xl, wr1, br1, xr, N);
  k2_kernel<4><<<(N + 3) / 4, 128, 0, stream>>>(xl, xr, row_ptr, csr_src, ea_csr,
                                                we1, at1, bc1, h, N);
  // layer 2: K=128 -> 128
  k1_kernel<128, 128, _Float16><<<dim3((N + 63) / 64, 2), 256, 0, stream>>>(
      h, wl2, bl2, xl, wr2, br2, xr, N);
  k2_kernel<4><<<(N + 3) / 4, 128, 0, stream>>>(xl, xr, row_ptr, csr_src, ea_csr,
                                                we2, at2, bc2, h, N);
  // layer 3: K=128 -> 32 (single head)
  k1_kernel<128, 32, _Float16><<<dim3((N + 255) / 256, 2), 256, 0, stream>>>(
      h, wl3, bl3, xl, wr3, br3, xr, N);
  k2_kernel<1><<<(N + 15) / 16, 128, 0, stream>>>(xl, xr, row_ptr, csr_src, ea_csr,
                                                  we3, at3, bc3, h, N);

  pool2_kernel<<<GNUM, 256, 0, stream>>>(h, gstart, gmean);
  fc_kernel<<<GNUM, 64, 0, stream>>>(gmean, wf1, bf1, wf2, bf2, (float*)d_out);
}

// Round 4
// 1104.075 us; speedup vs baseline: 1.8128x; 1.1917x over previous
//
#include <hip/hip_runtime.h>
#include <cstdint>
#include <type_traits>

// GNN GATv2 x3 + mean-pool + MLP.
// fp16 MFMA for the K=128 node-transform GEMMs (weights pre-packed into
// B-fragment order); fp16 feature tables + fp16 CSR-ordered edge features for
// the gather-heavy attention kernels. Self-loop inlined as last CSR entry.
constexpr int GNUM = 128;   // graphs

typedef _Float16 h4 __attribute__((ext_vector_type(4)));
typedef _Float16 h8 __attribute__((ext_vector_type(8)));
typedef float f4 __attribute__((ext_vector_type(4)));

// ---------------------------------------------------------------- setup kernels

__global__ __launch_bounds__(256) void hist_kernel(const int* __restrict__ dst,
                                                   int* __restrict__ cnt, int E) {
  int i = blockIdx.x * 256 + threadIdx.x;
  if (i < E) atomicAdd(&cnt[dst[i]], 1);
}

// exclusive scan of (cnt[i]+1): CSR with one extra self-loop slot per node
__global__ __launch_bounds__(1024) void scan_kernel(const int* __restrict__ cnt,
                                                    int* __restrict__ row_ptr,
                                                    int* __restrict__ fill, int n) {
  __shared__ int part[1024];
  int t = threadIdx.x;
  int chunk = (n + 1023) / 1024;
  int lo = t * chunk;
  if (lo > n) lo = n;
  int hi = lo + chunk;
  if (hi > n) hi = n;
  int s = 0;
  for (int i = lo; i < hi; i++) s += cnt[i] + 1;
  part[t] = s;
  __syncthreads();
  for (int off = 1; off < 1024; off <<= 1) {
    int v = (t >= off) ? part[t - off] : 0;
    __syncthreads();
    part[t] += v;
    __syncthreads();
  }
  int run = (t == 0) ? 0 : part[t - 1];
  for (int i = lo; i < hi; i++) {
    row_ptr[i] = run;
    fill[i] = run;
    run += cnt[i] + 1;
  }
  if (t == 0) row_ptr[n] = part[1023];
}

// scatter edges into CSR slots; write fp16 edge features directly in CSR order
__global__ __launch_bounds__(256) void scatter_kernel(const int* __restrict__ src,
                                                      const int* __restrict__ dst,
                                                      const float* __restrict__ ea,
                                                      int* __restrict__ fill,
                                                      int* __restrict__ csr_src,
                                                      _Float16* __restrict__ ea_csr, int E) {
  int i = blockIdx.x * 256 + threadIdx.x;
  if (i >= E) return;
  int d = dst[i];
  int p = atomicAdd(&fill[d], 1);
  csr_src[p] = src[i];
  float4 e0 = *(const float4*)&ea[(size_t)i * 8];
  float4 e1 = *(const float4*)&ea[(size_t)i * 8 + 4];
  h8 v;
  v[0] = (_Float16)e0.x; v[1] = (_Float16)e0.y; v[2] = (_Float16)e0.z; v[3] = (_Float16)e0.w;
  v[4] = (_Float16)e1.x; v[5] = (_Float16)e1.y; v[6] = (_Float16)e1.z; v[7] = (_Float16)e1.w;
  *(h8*)&ea_csr[(size_t)p * 8] = v;
}

// fill the self-loop slot (last of each segment): src=i, feature=mean of segment
__global__ __launch_bounds__(256) void selfloop_kernel(const int* __restrict__ row_ptr,
                                                       int* __restrict__ csr_src,
                                                       _Float16* __restrict__ ea_csr, int n) {
  int i = blockIdx.x * 256 + threadIdx.x;
  if (i >= n) return;
  int s = row_ptr[i], e = row_ptr[i + 1] - 1;   // [s,e) = real edges, e = self slot
  float a[8] = {0, 0, 0, 0, 0, 0, 0, 0};
  for (int j = s; j < e; j++) {
    h8 t = *(const h8*)&ea_csr[(size_t)j * 8];
#pragma unroll
    for (int k = 0; k < 8; k++) a[k] += (float)t[k];
  }
  float inv = 1.f / fmaxf((float)(e - s), 1.f);
  h8 o;
#pragma unroll
  for (int k = 0; k < 8; k++) o[k] = (_Float16)(a[k] * inv);
  *(h8*)&ea_csr[(size_t)e * 8] = o;
  csr_src[e] = i;
}

// pack w [K][NC] f32 -> fp16 MFMA B-fragment order:
// wp[((nt*KB + kb)*64 + lane)*8 + j] = w[kb*32 + (lane>>4)*8 + j][nt*16 + (lane&15)]
// blockIdx.y selects w0/w1.
__global__ __launch_bounds__(256) void pack_kernel(const float* __restrict__ w0,
                                                   _Float16* __restrict__ wp0,
                                                   const float* __restrict__ w1,
                                                   _Float16* __restrict__ wp1,
                                                   int K, int NC) {
  const float* w = blockIdx.y ? w1 : w0;
  _Float16* wp = blockIdx.y ? wp1 : wp0;
  int KB = K / 32;
  int total = (NC / 16) * KB * 64;
  int idx = blockIdx.x * 256 + threadIdx.x;
  if (idx >= total) return;
  int lane = idx & 63;
  int blk = idx >> 6;
  int nt = blk / KB, kb = blk % KB;
  int col = nt * 16 + (lane & 15);
  int krow = kb * 32 + (lane >> 4) * 8;
  h8 v;
#pragma unroll
  for (int j = 0; j < 8; j++) v[j] = (_Float16)w[(size_t)(krow + j) * NC + col];
  *(h8*)&wp[(size_t)idx * 8] = v;
}

// ---------------------------------------------------------------- node transform GEMMs

// f32 VALU path for layer 1 (K=16, tiny): out = x@w + b, fp16 output
template <int K, int NCOLS>
__global__ __launch_bounds__(256) void k1_kernel(const float* __restrict__ x,
                                                 const float* __restrict__ w0,
                                                 const float* __restrict__ b0,
                                                 _Float16* __restrict__ out0,
                                                 const float* __restrict__ w1,
                                                 const float* __restrict__ b1,
                                                 _Float16* __restrict__ out1, int n) {
  constexpr int KC = (K < 32) ? K : 32;
  constexpr int CG = NCOLS / 4;
  constexpr int NG = 256 / CG;
  constexpr int MTILE = NG * 8;
  constexpr int XS = KC + 4;
  __shared__ float xs[MTILE * XS];
  __shared__ float ws[KC * NCOLS];

  const float* w = blockIdx.y ? w1 : w0;
  const float* b = blockIdx.y ? b1 : b0;
  _Float16* out = blockIdx.y ? out1 : out0;

  int tid = threadIdx.x;
  int cg = tid % CG, ng = tid / CG;
  int c0 = 4 * cg, n0 = 8 * ng;
  int node0 = blockIdx.x * MTILE;

  float acc[8][4] = {};

  for (int k0 = 0; k0 < K; k0 += KC) {
    for (int idx = tid; idx < MTILE * KC / 4; idx += 256) {
      int nl = idx / (KC / 4), kq = idx % (KC / 4);
      int gn = node0 + nl;
      float4 v = make_float4(0.f, 0.f, 0.f, 0.f);
      if (gn < n) v = *(const float4*)&x[(size_t)gn * K + k0 + 4 * kq];
      *(float4*)&xs[nl * XS + 4 * kq] = v;
    }
    for (int idx = tid; idx < KC * NCOLS / 4; idx += 256) {
      int kr = idx / (NCOLS / 4), cq = idx % (NCOLS / 4);
      *(float4*)&ws[kr * NCOLS + 4 * cq] =
          *(const float4*)&w[(size_t)(k0 + kr) * NCOLS + 4 * cq];
    }
    __syncthreads();
#pragma unroll
    for (int kk = 0; kk < KC; kk += 4) {
      float4 wv0 = *(const float4*)&ws[(kk + 0) * NCOLS + c0];
      float4 wv1 = *(const float4*)&ws[(kk + 1) * NCOLS + c0];
      float4 wv2 = *(const float4*)&ws[(kk + 2) * NCOLS + c0];
      float4 wv3 = *(const float4*)&ws[(kk + 3) * NCOLS + c0];
#pragma unroll
      for (int j = 0; j < 8; j++) {
        float4 xv = *(const float4*)&xs[(n0 + j) * XS + kk];
        acc[j][0] += xv.x * wv0.x + xv.y * wv1.x + xv.z * wv2.x + xv.w * wv3.x;
        acc[j][1] += xv.x * wv0.y + xv.y * wv1.y + xv.z * wv2.y + xv.w * wv3.y;
        acc[j][2] += xv.x * wv0.z + xv.y * wv1.z + xv.z * wv2.z + xv.w * wv3.z;
        acc[j][3] += xv.x * wv0.w + xv.y * wv1.w + xv.z * wv2.w + xv.w * wv3.w;
      }
    }
    __syncthreads();
  }

  float4 bv = *(const float4*)&b[c0];
#pragma unroll
  for (int j = 0; j < 8; j++) {
    int gn = node0 + n0 + j;
    if (gn < n) {
      h4 o;
      o[0] = (_Float16)(acc[j][0] + bv.x);
      o[1] = (_Float16)(acc[j][1] + bv.y);
      o[2] = (_Float16)(acc[j][2] + bv.z);
      o[3] = (_Float16)(acc[j][3] + bv.w);
      *(h4*)&out[(size_t)gn * NCOLS + c0] = o;
    }
  }
}

// fp16 MFMA path for K=128 GEMMs. x fp16 [n,K]; wp pre-packed B-fragments;
// out fp16 [n,NCOLS]. 256 thr = 4 waves, 16 nodes/wave, 64 nodes/block.
template <int K, int NCOLS>
__global__ __launch_bounds__(256) void k1m_kernel(const _Float16* __restrict__ x,
                                                  const _Float16* __restrict__ wp0,
                                                  const float* __restrict__ b0,
                                                  _Float16* __restrict__ out0,
                                                  const _Float16* __restrict__ wp1,
                                                  const float* __restrict__ b1,
                                                  _Float16* __restrict__ out1, int n) {
  constexpr int NT = NCOLS / 16, KB = K / 32;
  const _Float16* wp = blockIdx.y ? wp1 : wp0;
  const float* b = blockIdx.y ? b1 : b0;
  _Float16* out = blockIdx.y ? out1 : out0;

  int tid = threadIdx.x;
  int wave = tid >> 6, lane = tid & 63;
  int m = lane & 15, quad = lane >> 4;
  int node0 = blockIdx.x * 64 + wave * 16;

  // A fragments: A[m=lane&15][k=quad*8+j], one 16B load per k-block
  h8 afrag[KB];
  int anode = node0 + m;
  if (anode < n) {
#pragma unroll
    for (int kb = 0; kb < KB; kb++)
      afrag[kb] = *(const h8*)&x[(size_t)anode * K + kb * 32 + quad * 8];
  } else {
#pragma unroll
    for (int kb = 0; kb < KB; kb++) afrag[kb] = (h8)(_Float16)0.f;
  }

  f4 acc[NT] = {};
#pragma unroll
  for (int nt = 0; nt < NT; nt++) {
#pragma unroll
    for (int kb = 0; kb < KB; kb++) {
      h8 bfrag = *(const h8*)&wp[((size_t)(nt * KB + kb) * 64 + lane) * 8];
      acc[nt] = __builtin_amdgcn_mfma_f32_16x16x32_f16(afrag[kb], bfrag, acc[nt], 0, 0, 0);
    }
  }

  // C/D: col=lane&15, row=quad*4+reg
#pragma unroll
  for (int nt = 0; nt < NT; nt++) {
#pragma unroll
    for (int r = 0; r < 4; r++) {
      int row = node0 + quad * 4 + r;
      if (row < n) {
        int col = nt * 16 + m;
        out[(size_t)row * NCOLS + col] = (_Float16)(acc[nt][r] + b[col]);
      }
    }
  }
}

// ---------------------------------------------------------------- fused GATv2 edge+softmax+aggregate
// One-pass softmax (no max-shift; logits O(1)). Self-loop is a normal CSR entry.
// 8 lanes per head, 4 channels per lane. H in {4 (HC=128), 1 (HC=32)}.
template <int H>
__global__ __launch_bounds__(128) void k2_kernel(
    const _Float16* __restrict__ xl, const _Float16* __restrict__ xr,
    const int* __restrict__ row_ptr, const int* __restrict__ csr_src,
    const _Float16* __restrict__ ea_csr, const float* __restrict__ we,
    const float* __restrict__ att, const float* __restrict__ bc,
    _Float16* __restrict__ out, int n) {
  constexpr int HC = H * 32;
  constexpr int NL = HC / 4;   // lanes per node (32 or 8)
  constexpr int NPB = 128 / NL;

  int tid = threadIdx.x;
  int ln = tid / NL, q = tid % NL;
  int c0 = 4 * q;
  int node = blockIdx.x * NPB + ln;
  if (node >= n) return;

  float wreg[8][4];
#pragma unroll
  for (int k = 0; k < 8; k++) {
    float4 v = *(const float4*)&we[k * HC + c0];
    wreg[k][0] = v.x; wreg[k][1] = v.y; wreg[k][2] = v.z; wreg[k][3] = v.w;
  }
  float4 av = *(const float4*)&att[c0];
  float atr[4] = {av.x, av.y, av.z, av.w};
  h4 xrh = *(const h4*)&xr[(size_t)node * HC + c0];
  float xrr[4] = {(float)xrh[0], (float)xrh[1], (float)xrh[2], (float)xrh[3]};

  float acc[4] = {0.f, 0.f, 0.f, 0.f};
  float s = 0.f;

  int start = row_ptr[node], end = row_ptr[node + 1];
  for (int j = start; j < end; j++) {
    int src = csr_src[j];
    h8 eh = *(const h8*)&ea_csr[(size_t)j * 8];
    h4 xlh = *(const h4*)&xl[(size_t)src * HC + c0];
    float ev[8];
#pragma unroll
    for (int k = 0; k < 8; k++) ev[k] = (float)eh[k];
    float xlv[4] = {(float)xlh[0], (float)xlh[1], (float)xlh[2], (float)xlh[3]};

    float part = 0.f;
#pragma unroll
    for (int i = 0; i < 4; i++) {
      float t = xlv[i] + xrr[i];
#pragma unroll
      for (int k = 0; k < 8; k++) t += ev[k] * wreg[k][i];
      t = fmaxf(t, 0.2f * t);        // leaky_relu(t, 0.2)
      part += t * atr[i];
    }
    part += __shfl_xor(part, 1, 64);
    part += __shfl_xor(part, 2, 64);
    part += __shfl_xor(part, 4, 64);
    float p = __expf(part);
    s += p;
#pragma unroll
    for (int i = 0; i < 4; i++) acc[i] += p * xlv[i];
  }

  float inv = 1.f / (s + 1e-16f);
  h4 o;
#pragma unroll
  for (int i = 0; i < 4; i++) {
    float v = acc[i] * inv + bc[c0 + i];
    o[i] = (_Float16)(v > 0.f ? v : (__expf(v) - 1.f));   // elu
  }
  *(h4*)&out[(size_t)node * HC + c0] = o;
}

// ---------------------------------------------------------------- pooling + MLP

__global__ __launch_bounds__(256) void gbound_kernel(const int* __restrict__ batch,
                                                     int* __restrict__ gstart, int n) {
  int g = blockIdx.x * 256 + threadIdx.x;
  if (g > GNUM) return;
  int lo = 0, hi = n;
  while (lo < hi) {
    int mid = (lo + hi) >> 1;
    if (batch[mid] < g) lo = mid + 1; else hi = mid;
  }
  gstart[g] = lo;
}

__global__ __launch_bounds__(256) void pool2_kernel(const _Float16* __restrict__ h,
                                                    const int* __restrict__ gstart,
                                                    float* __restrict__ gmean) {
  __shared__ float red[256];
  int g = blockIdx.x;
  int t = threadIdx.x;
  int s = gstart[g], e = gstart[g + 1];
  int c = t & 31, rg = t >> 5;
  float acc = 0.f;
  for (int i = s + rg; i < e; i += 8) acc += (float)h[(size_t)i * 32 + c];
  red[t] = acc;
  __syncthreads();
  if (t < 128) red[t] += red[t + 128];
  __syncthreads();
  if (t < 64) red[t] += red[t + 64];
  __syncthreads();
  if (t < 32) {
    float v = red[t] + red[t + 32];
    gmean[g * 32 + t] = v / fmaxf((float)(e - s), 1.f);
  }
}

__global__ __launch_bounds__(64) void fc_kernel(const float* __restrict__ gmean,
                                                const float* __restrict__ w1,
                                                const float* __restrict__ b1,
                                                const float* __restrict__ w2,
                                                const float* __restrict__ b2,
                                                float* __restrict__ out) {
  __shared__ float g[32];
  __shared__ float a1[64];
  int gi = blockIdx.x;
  int t = threadIdx.x;
  if (t < 32) g[t] = gmean[gi * 32 + t];
  __syncthreads();
  float v = b1[t];
  for (int k = 0; k < 32; k++) v += g[k] * w1[k * 64 + t];
  a1[t] = v > 0.f ? v : (__expf(v) - 1.f);
  __syncthreads();
  if (t < 4) {
    float o = b2[t];
    for (int k = 0; k < 64; k++) o += a1[k] * w2[k * 4 + t];
    out[gi * 4 + t] = o;
  }
}

// ---------------------------------------------------------------- launch

extern "C" void kernel_launch(void* const* d_in, const int* in_sizes, int n_in,
                              void* d_out, int out_size, void* d_ws, size_t ws_size,
                              hipStream_t stream) {
  const float* x     = (const float*)d_in[0];
  const int*   ei    = (const int*)d_in[1];
  const float* eattr = (const float*)d_in[2];
  const int*   batch = (const int*)d_in[3];
  const float *wl1 = (const float*)d_in[4],  *bl1 = (const float*)d_in[5];
  const float *wr1 = (const float*)d_in[6],  *br1 = (const float*)d_in[7];
  const float *we1 = (const float*)d_in[8],  *at1 = (const float*)d_in[9];
  const float *bc1 = (const float*)d_in[10];
  const float *wl2 = (const float*)d_in[11], *bl2 = (const float*)d_in[12];
  const float *wr2 = (const float*)d_in[13], *br2 = (const float*)d_in[14];
  const float *we2 = (const float*)d_in[15], *at2 = (const float*)d_in[16];
  const float *bc2 = (const float*)d_in[17];
  const float *wl3 = (const float*)d_in[18], *bl3 = (const float*)d_in[19];
  const float *wr3 = (const float*)d_in[20], *br3 = (const float*)d_in[21];
  const float *we3 = (const float*)d_in[22], *at3 = (const float*)d_in[23];
  const float *bc3 = (const float*)d_in[24];
  const float *wf1 = (const float*)d_in[25], *bf1 = (const float*)d_in[26];
  const float *wf2 = (const float*)d_in[27], *bf2 = (const float*)d_in[28];

  int N = in_sizes[0] / 16;
  int E = in_sizes[1] / 2;
  const int* srcp = ei;
  const int* dstp = ei + E;
  int EA = E + N;   // CSR entries incl. self-loops

  char* wsb = (char*)d_ws;
  size_t off = 0;
  auto alloc = [&](size_t bytes) -> char* {
    char* p = wsb + off;
    off += (bytes + 255) & ~(size_t)255;
    return p;
  };
  int*       cnt     = (int*)alloc((size_t)N * 4);
  int*       row_ptr = (int*)alloc((size_t)(N + 1) * 4);
  int*       fill    = (int*)alloc((size_t)N * 4);
  int*       csr_src = (int*)alloc((size_t)EA * 4);
  _Float16*  ea_csr  = (_Float16*)alloc((size_t)EA * 8 * 2);
  _Float16*  xl      = (_Float16*)alloc((size_t)N * 128 * 2);
  _Float16*  xr      = (_Float16*)alloc((size_t)N * 128 * 2);
  _Float16*  h16     = (_Float16*)alloc((size_t)N * 128 * 2);
  _Float16*  h3      = (_Float16*)alloc((size_t)N * 32 * 2);
  float*     gmean   = (float*)alloc((size_t)GNUM * 32 * 4);
  int*       gstart  = (int*)alloc((size_t)(GNUM + 1) * 4);
  _Float16*  wp2l    = (_Float16*)alloc((size_t)128 * 128 * 2);
  _Float16*  wp2r    = (_Float16*)alloc((size_t)128 * 128 * 2);
  _Float16*  wp3l    = (_Float16*)alloc((size_t)128 * 32 * 2);
  _Float16*  wp3r    = (_Float16*)alloc((size_t)128 * 32 * 2);

  hipMemsetAsync(cnt, 0, (size_t)N * 4, stream);

  hist_kernel<<<(E + 255) / 256, 256, 0, stream>>>(dstp, cnt, E);
  scan_kernel<<<1, 1024, 0, stream>>>(cnt, row_ptr, fill, N);
  scatter_kernel<<<(E + 255) / 256, 256, 0, stream>>>(srcp, dstp, eattr, fill, csr_src, ea_csr, E);
  selfloop_kernel<<<(N + 255) / 256, 256, 0, stream>>>(row_ptr, csr_src, ea_csr, N);
  gbound_kernel<<<1, 256, 0, stream>>>(batch, gstart, N);
  // pack MFMA weights: (NC/16)*(K/32)*64 threads each
  pack_kernel<<<dim3(8, 2), 256, 0, stream>>>(wl2, wp2l, wr2, wp2r, 128, 128);
  pack_kernel<<<dim3(2, 2), 256, 0, stream>>>(wl3, wp3l, wr3, wp3r, 128, 32);

  // layer 1: K=16 -> 128 (f32 VALU, cheap)
  k1_kernel<16, 128><<<dim3((N + 63) / 64, 2), 256, 0, stream>>>(
      x, wl1, bl1, xl, wr1, br1, xr, N);
  k2_kernel<4><<<(N + 3) / 4, 128, 0, stream>>>(xl, xr, row_ptr, csr_src, ea_csr,
                                                we1, at1, bc1, h16, N);
  // layer 2: K=128 -> 128 (fp16 MFMA)
  k1m_kernel<128, 128><<<dim3((N + 63) / 64, 2), 256, 0, stream>>>(
      h16, wp2l, bl2, xl, wp2r, br2, xr, N);
  k2_kernel<4><<<(N + 3) / 4, 128, 0, stream>>>(xl, xr, row_ptr, csr_src, ea_csr,
                                                we2, at2, bc2, h16, N);
  // layer 3: K=128 -> 32 (fp16 MFMA, single head)
  k1m_kernel<128, 32><<<dim3((N + 63) / 64, 2), 256, 0, stream>>>(
      h16, wp3l, bl3, xl, wp3r, br3, xr, N);
  k2_kernel<1><<<(N + 15) / 16, 128, 0, stream>>>(xl, xr, row_ptr, csr_src, ea_csr,
                                                  we3, at3, bc3, h3, N);

  pool2_kernel<<<GNUM, 256, 0, stream>>>(h3, gstart, gmean);
  fc_kernel<<<GNUM, 64, 0, stream>>>(gmean, wf1, bf1, wf2, bf2, (float*)d_out);
}

// Round 5
// 891.097 us; speedup vs baseline: 2.2461x; 1.2390x over previous
//
#include <hip/hip_runtime.h>
#include <cstdint>
#include <type_traits>

// GNN GATv2 x3 + mean-pool + MLP.
// fp16 MFMA for the K=128 node-transform GEMMs (weights pre-packed into
// B-fragment order); fp16 feature tables + fp16 CSR-ordered edge features for
// the gather-heavy attention kernels. Self-loop inlined as last CSR entry.
// CSR row_ptr built with a 3-phase parallel scan (R4: the single-block scan
// was 228 us, 21% of total, at 0.15% occupancy).
constexpr int GNUM = 128;   // graphs

typedef _Float16 h4 __attribute__((ext_vector_type(4)));
typedef _Float16 h8 __attribute__((ext_vector_type(8)));
typedef float f4 __attribute__((ext_vector_type(4)));

// ---------------------------------------------------------------- setup kernels

__global__ __launch_bounds__(256) void hist_kernel(const int* __restrict__ dst,
                                                   int* __restrict__ cnt, int E) {
  int i = blockIdx.x * 256 + threadIdx.x;
  if (i < E) atomicAdd(&cnt[dst[i]], 1);
}

// ---- 3-phase parallel exclusive scan of (cnt[i]+1), 512 elems per block ----
__global__ __launch_bounds__(256) void scan_part_kernel(const int* __restrict__ cnt,
                                                        int* __restrict__ bpart, int n) {
  __shared__ int red[256];
  int base = blockIdx.x * 512;
  int t = threadIdx.x;
  int s = 0;
  int i0 = base + t, i1 = base + 256 + t;
  if (i0 < n) s += cnt[i0] + 1;
  if (i1 < n) s += cnt[i1] + 1;
  red[t] = s;
  __syncthreads();
  for (int off = 128; off > 0; off >>= 1) {
    if (t < off) red[t] += red[t + off];
    __syncthreads();
  }
  if (t == 0) bpart[blockIdx.x] = red[0];
}

__global__ __launch_bounds__(1024) void scan_top_kernel(const int* __restrict__ bpart,
                                                        int* __restrict__ boff,
                                                        int* __restrict__ row_ptr,
                                                        int B, int n) {
  __shared__ int buf[1024];
  int t = threadIdx.x;
  buf[t] = (t < B) ? bpart[t] : 0;
  __syncthreads();
  for (int off = 1; off < 1024; off <<= 1) {
    int v = (t >= off) ? buf[t - off] : 0;
    __syncthreads();
    buf[t] += v;
    __syncthreads();
  }
  if (t < B) boff[t] = (t == 0) ? 0 : buf[t - 1];
  if (t == 0) row_ptr[n] = buf[1023];
}

__global__ __launch_bounds__(256) void scan_write_kernel(const int* __restrict__ cnt,
                                                         const int* __restrict__ boff,
                                                         int* __restrict__ row_ptr,
                                                         int* __restrict__ fill, int n) {
  __shared__ int red[256];
  int base = blockIdx.x * 512;
  int t = threadIdx.x;
  int i0 = base + 2 * t, i1 = base + 2 * t + 1;
  int v0 = (i0 < n) ? cnt[i0] + 1 : 0;
  int v1 = (i1 < n) ? cnt[i1] + 1 : 0;
  int val = v0 + v1;
  red[t] = val;
  __syncthreads();
  for (int off = 1; off < 256; off <<= 1) {
    int u = (t >= off) ? red[t - off] : 0;
    __syncthreads();
    red[t] += u;
    __syncthreads();
  }
  int o = boff[blockIdx.x] + red[t] - val;   // exclusive prefix for this pair
  if (i0 < n) { row_ptr[i0] = o; fill[i0] = o; }
  if (i1 < n) { row_ptr[i1] = o + v0; fill[i1] = o + v0; }
}

// scatter edges into CSR slots; write fp16 edge features directly in CSR order
__global__ __launch_bounds__(256) void scatter_kernel(const int* __restrict__ src,
                                                      const int* __restrict__ dst,
                                                      const float* __restrict__ ea,
                                                      int* __restrict__ fill,
                                                      int* __restrict__ csr_src,
                                                      _Float16* __restrict__ ea_csr, int E) {
  int i = blockIdx.x * 256 + threadIdx.x;
  if (i >= E) return;
  int d = dst[i];
  int p = atomicAdd(&fill[d], 1);
  csr_src[p] = src[i];
  float4 e0 = *(const float4*)&ea[(size_t)i * 8];
  float4 e1 = *(const float4*)&ea[(size_t)i * 8 + 4];
  h8 v;
  v[0] = (_Float16)e0.x; v[1] = (_Float16)e0.y; v[2] = (_Float16)e0.z; v[3] = (_Float16)e0.w;
  v[4] = (_Float16)e1.x; v[5] = (_Float16)e1.y; v[6] = (_Float16)e1.z; v[7] = (_Float16)e1.w;
  *(h8*)&ea_csr[(size_t)p * 8] = v;
}

// fill the self-loop slot (last of each segment): src=i, feature=mean of segment
__global__ __launch_bounds__(256) void selfloop_kernel(const int* __restrict__ row_ptr,
                                                       int* __restrict__ csr_src,
                                                       _Float16* __restrict__ ea_csr, int n) {
  int i = blockIdx.x * 256 + threadIdx.x;
  if (i >= n) return;
  int s = row_ptr[i], e = row_ptr[i + 1] - 1;   // [s,e) = real edges, e = self slot
  float a[8] = {0, 0, 0, 0, 0, 0, 0, 0};
  for (int j = s; j < e; j++) {
    h8 t = *(const h8*)&ea_csr[(size_t)j * 8];
#pragma unroll
    for (int k = 0; k < 8; k++) a[k] += (float)t[k];
  }
  float inv = 1.f / fmaxf((float)(e - s), 1.f);
  h8 o;
#pragma unroll
  for (int k = 0; k < 8; k++) o[k] = (_Float16)(a[k] * inv);
  *(h8*)&ea_csr[(size_t)e * 8] = o;
  csr_src[e] = i;
}

// pack w [K][NC] f32 -> fp16 MFMA B-fragment order:
// wp[((nt*KB + kb)*64 + lane)*8 + j] = w[kb*32 + (lane>>4)*8 + j][nt*16 + (lane&15)]
__global__ __launch_bounds__(256) void pack_kernel(const float* __restrict__ w0,
                                                   _Float16* __restrict__ wp0,
                                                   const float* __restrict__ w1,
                                                   _Float16* __restrict__ wp1,
                                                   int K, int NC) {
  const float* w = blockIdx.y ? w1 : w0;
  _Float16* wp = blockIdx.y ? wp1 : wp0;
  int KB = K / 32;
  int total = (NC / 16) * KB * 64;
  int idx = blockIdx.x * 256 + threadIdx.x;
  if (idx >= total) return;
  int lane = idx & 63;
  int blk = idx >> 6;
  int nt = blk / KB, kb = blk % KB;
  int col = nt * 16 + (lane & 15);
  int krow = kb * 32 + (lane >> 4) * 8;
  h8 v;
#pragma unroll
  for (int j = 0; j < 8; j++) v[j] = (_Float16)w[(size_t)(krow + j) * NC + col];
  *(h8*)&wp[(size_t)idx * 8] = v;
}

// ---------------------------------------------------------------- node transform GEMMs

// f32 VALU path for layer 1 (K=16, tiny): out = x@w + b, fp16 output
template <int K, int NCOLS>
__global__ __launch_bounds__(256) void k1_kernel(const float* __restrict__ x,
                                                 const float* __restrict__ w0,
                                                 const float* __restrict__ b0,
                                                 _Float16* __restrict__ out0,
                                                 const float* __restrict__ w1,
                                                 const float* __restrict__ b1,
                                                 _Float16* __restrict__ out1, int n) {
  constexpr int KC = (K < 32) ? K : 32;
  constexpr int CG = NCOLS / 4;
  constexpr int NG = 256 / CG;
  constexpr int MTILE = NG * 8;
  constexpr int XS = KC + 4;
  __shared__ float xs[MTILE * XS];
  __shared__ float ws[KC * NCOLS];

  const float* w = blockIdx.y ? w1 : w0;
  const float* b = blockIdx.y ? b1 : b0;
  _Float16* out = blockIdx.y ? out1 : out0;

  int tid = threadIdx.x;
  int cg = tid % CG, ng = tid / CG;
  int c0 = 4 * cg, n0 = 8 * ng;
  int node0 = blockIdx.x * MTILE;

  float acc[8][4] = {};

  for (int k0 = 0; k0 < K; k0 += KC) {
    for (int idx = tid; idx < MTILE * KC / 4; idx += 256) {
      int nl = idx / (KC / 4), kq = idx % (KC / 4);
      int gn = node0 + nl;
      float4 v = make_float4(0.f, 0.f, 0.f, 0.f);
      if (gn < n) v = *(const float4*)&x[(size_t)gn * K + k0 + 4 * kq];
      *(float4*)&xs[nl * XS + 4 * kq] = v;
    }
    for (int idx = tid; idx < KC * NCOLS / 4; idx += 256) {
      int kr = idx / (NCOLS / 4), cq = idx % (NCOLS / 4);
      *(float4*)&ws[kr * NCOLS + 4 * cq] =
          *(const float4*)&w[(size_t)(k0 + kr) * NCOLS + 4 * cq];
    }
    __syncthreads();
#pragma unroll
    for (int kk = 0; kk < KC; kk += 4) {
      float4 wv0 = *(const float4*)&ws[(kk + 0) * NCOLS + c0];
      float4 wv1 = *(const float4*)&ws[(kk + 1) * NCOLS + c0];
      float4 wv2 = *(const float4*)&ws[(kk + 2) * NCOLS + c0];
      float4 wv3 = *(const float4*)&ws[(kk + 3) * NCOLS + c0];
#pragma unroll
      for (int j = 0; j < 8; j++) {
        float4 xv = *(const float4*)&xs[(n0 + j) * XS + kk];
        acc[j][0] += xv.x * wv0.x + xv.y * wv1.x + xv.z * wv2.x + xv.w * wv3.x;
        acc[j][1] += xv.x * wv0.y + xv.y * wv1.y + xv.z * wv2.y + xv.w * wv3.y;
        acc[j][2] += xv.x * wv0.z + xv.y * wv1.z + xv.z * wv2.z + xv.w * wv3.z;
        acc[j][3] += xv.x * wv0.w + xv.y * wv1.w + xv.z * wv2.w + xv.w * wv3.w;
      }
    }
    __syncthreads();
  }

  float4 bv = *(const float4*)&b[c0];
#pragma unroll
  for (int j = 0; j < 8; j++) {
    int gn = node0 + n0 + j;
    if (gn < n) {
      h4 o;
      o[0] = (_Float16)(acc[j][0] + bv.x);
      o[1] = (_Float16)(acc[j][1] + bv.y);
      o[2] = (_Float16)(acc[j][2] + bv.z);
      o[3] = (_Float16)(acc[j][3] + bv.w);
      *(h4*)&out[(size_t)gn * NCOLS + c0] = o;
    }
  }
}

// fp16 MFMA path for K=128 GEMMs. x fp16 [n,K]; wp pre-packed B-fragments;
// out fp16 [n,NCOLS]. 256 thr = 4 waves, 16 nodes/wave, 64 nodes/block.
template <int K, int NCOLS>
__global__ __launch_bounds__(256) void k1m_kernel(const _Float16* __restrict__ x,
                                                  const _Float16* __restrict__ wp0,
                                                  const float* __restrict__ b0,
                                                  _Float16* __restrict__ out0,
                                                  const _Float16* __restrict__ wp1,
                                                  const float* __restrict__ b1,
                                                  _Float16* __restrict__ out1, int n) {
  constexpr int NT = NCOLS / 16, KB = K / 32;
  const _Float16* wp = blockIdx.y ? wp1 : wp0;
  const float* b = blockIdx.y ? b1 : b0;
  _Float16* out = blockIdx.y ? out1 : out0;

  int tid = threadIdx.x;
  int wave = tid >> 6, lane = tid & 63;
  int m = lane & 15, quad = lane >> 4;
  int node0 = blockIdx.x * 64 + wave * 16;

  // A fragments: A[m=lane&15][k=quad*8+j], one 16B load per k-block
  h8 afrag[KB];
  int anode = node0 + m;
  if (anode < n) {
#pragma unroll
    for (int kb = 0; kb < KB; kb++)
      afrag[kb] = *(const h8*)&x[(size_t)anode * K + kb * 32 + quad * 8];
  } else {
#pragma unroll
    for (int kb = 0; kb < KB; kb++) afrag[kb] = (h8)(_Float16)0.f;
  }

  f4 acc[NT] = {};
#pragma unroll
  for (int nt = 0; nt < NT; nt++) {
#pragma unroll
    for (int kb = 0; kb < KB; kb++) {
      h8 bfrag = *(const h8*)&wp[((size_t)(nt * KB + kb) * 64 + lane) * 8];
      acc[nt] = __builtin_amdgcn_mfma_f32_16x16x32_f16(afrag[kb], bfrag, acc[nt], 0, 0, 0);
    }
  }

  // C/D: col=lane&15, row=quad*4+reg
#pragma unroll
  for (int nt = 0; nt < NT; nt++) {
#pragma unroll
    for (int r = 0; r < 4; r++) {
      int row = node0 + quad * 4 + r;
      if (row < n) {
        int col = nt * 16 + m;
        out[(size_t)row * NCOLS + col] = (_Float16)(acc[nt][r] + b[col]);
      }
    }
  }
}

// ---------------------------------------------------------------- fused GATv2 edge+softmax+aggregate
// One-pass softmax (no max-shift; logits O(1)). Self-loop is a normal CSR entry.
// 8 lanes per head, 4 channels per lane. H in {4 (HC=128), 1 (HC=32)}.
template <int H>
__global__ __launch_bounds__(128) void k2_kernel(
    const _Float16* __restrict__ xl, const _Float16* __restrict__ xr,
    const int* __restrict__ row_ptr, const int* __restrict__ csr_src,
    const _Float16* __restrict__ ea_csr, const float* __restrict__ we,
    const float* __restrict__ att, const float* __restrict__ bc,
    _Float16* __restrict__ out, int n) {
  constexpr int HC = H * 32;
  constexpr int NL = HC / 4;   // lanes per node (32 or 8)
  constexpr int NPB = 128 / NL;

  int tid = threadIdx.x;
  int ln = tid / NL, q = tid % NL;
  int c0 = 4 * q;
  int node = blockIdx.x * NPB + ln;
  if (node >= n) return;

  float wreg[8][4];
#pragma unroll
  for (int k = 0; k < 8; k++) {
    float4 v = *(const float4*)&we[k * HC + c0];
    wreg[k][0] = v.x; wreg[k][1] = v.y; wreg[k][2] = v.z; wreg[k][3] = v.w;
  }
  float4 av = *(const float4*)&att[c0];
  float atr[4] = {av.x, av.y, av.z, av.w};
  h4 xrh = *(const h4*)&xr[(size_t)node * HC + c0];
  float xrr[4] = {(float)xrh[0], (float)xrh[1], (float)xrh[2], (float)xrh[3]};

  float acc[4] = {0.f, 0.f, 0.f, 0.f};
  float s = 0.f;

  int start = row_ptr[node], end = row_ptr[node + 1];
  for (int j = start; j < end; j++) {
    int src = csr_src[j];
    h8 eh = *(const h8*)&ea_csr[(size_t)j * 8];
    h4 xlh = *(const h4*)&xl[(size_t)src * HC + c0];
    float ev[8];
#pragma unroll
    for (int k = 0; k < 8; k++) ev[k] = (float)eh[k];
    float xlv[4] = {(float)xlh[0], (float)xlh[1], (float)xlh[2], (float)xlh[3]};

    float part = 0.f;
#pragma unroll
    for (int i = 0; i < 4; i++) {
      float t = xlv[i] + xrr[i];
#pragma unroll
      for (int k = 0; k < 8; k++) t += ev[k] * wreg[k][i];
      t = fmaxf(t, 0.2f * t);        // leaky_relu(t, 0.2)
      part += t * atr[i];
    }
    part += __shfl_xor(part, 1, 64);
    part += __shfl_xor(part, 2, 64);
    part += __shfl_xor(part, 4, 64);
    float p = __expf(part);
    s += p;
#pragma unroll
    for (int i = 0; i < 4; i++) acc[i] += p * xlv[i];
  }

  float inv = 1.f / (s + 1e-16f);
  h4 o;
#pragma unroll
  for (int i = 0; i < 4; i++) {
    float v = acc[i] * inv + bc[c0 + i];
    o[i] = (_Float16)(v > 0.f ? v : (__expf(v) - 1.f));   // elu
  }
  *(h4*)&out[(size_t)node * HC + c0] = o;
}

// ---------------------------------------------------------------- pooling + MLP

__global__ __launch_bounds__(256) void gbound_kernel(const int* __restrict__ batch,
                                                     int* __restrict__ gstart, int n) {
  int g = blockIdx.x * 256 + threadIdx.x;
  if (g > GNUM) return;
  int lo = 0, hi = n;
  while (lo < hi) {
    int mid = (lo + hi) >> 1;
    if (batch[mid] < g) lo = mid + 1; else hi = mid;
  }
  gstart[g] = lo;
}

__global__ __launch_bounds__(256) void pool2_kernel(const _Float16* __restrict__ h,
                                                    const int* __restrict__ gstart,
                                                    float* __restrict__ gmean) {
  __shared__ float red[256];
  int g = blockIdx.x;
  int t = threadIdx.x;
  int s = gstart[g], e = gstart[g + 1];
  int c = t & 31, rg = t >> 5;
  float acc = 0.f;
  for (int i = s + rg; i < e; i += 8) acc += (float)h[(size_t)i * 32 + c];
  red[t] = acc;
  __syncthreads();
  if (t < 128) red[t] += red[t + 128];
  __syncthreads();
  if (t < 64) red[t] += red[t + 64];
  __syncthreads();
  if (t < 32) {
    float v = red[t] + red[t + 32];
    gmean[g * 32 + t] = v / fmaxf((float)(e - s), 1.f);
  }
}

__global__ __launch_bounds__(64) void fc_kernel(const float* __restrict__ gmean,
                                                const float* __restrict__ w1,
                                                const float* __restrict__ b1,
                                                const float* __restrict__ w2,
                                                const float* __restrict__ b2,
                                                float* __restrict__ out) {
  __shared__ float g[32];
  __shared__ float a1[64];
  int gi = blockIdx.x;
  int t = threadIdx.x;
  if (t < 32) g[t] = gmean[gi * 32 + t];
  __syncthreads();
  float v = b1[t];
  for (int k = 0; k < 32; k++) v += g[k] * w1[k * 64 + t];
  a1[t] = v > 0.f ? v : (__expf(v) - 1.f);
  __syncthreads();
  if (t < 4) {
    float o = b2[t];
    for (int k = 0; k < 64; k++) o += a1[k] * w2[k * 4 + t];
    out[gi * 4 + t] = o;
  }
}

// ---------------------------------------------------------------- launch

extern "C" void kernel_launch(void* const* d_in, const int* in_sizes, int n_in,
                              void* d_out, int out_size, void* d_ws, size_t ws_size,
                              hipStream_t stream) {
  const float* x     = (const float*)d_in[0];
  const int*   ei    = (const int*)d_in[1];
  const float* eattr = (const float*)d_in[2];
  const int*   batch = (const int*)d_in[3];
  const float *wl1 = (const float*)d_in[4],  *bl1 = (const float*)d_in[5];
  const float *wr1 = (const float*)d_in[6],  *br1 = (const float*)d_in[7];
  const float *we1 = (const float*)d_in[8],  *at1 = (const float*)d_in[9];
  const float *bc1 = (const float*)d_in[10];
  const float *wl2 = (const float*)d_in[11], *bl2 = (const float*)d_in[12];
  const float *wr2 = (const float*)d_in[13], *br2 = (const float*)d_in[14];
  const float *we2 = (const float*)d_in[15], *at2 = (const float*)d_in[16];
  const float *bc2 = (const float*)d_in[17];
  const float *wl3 = (const float*)d_in[18], *bl3 = (const float*)d_in[19];
  const float *wr3 = (const float*)d_in[20], *br3 = (const float*)d_in[21];
  const float *we3 = (const float*)d_in[22], *at3 = (const float*)d_in[23];
  const float *bc3 = (const float*)d_in[24];
  const float *wf1 = (const float*)d_in[25], *bf1 = (const float*)d_in[26];
  const float *wf2 = (const float*)d_in[27], *bf2 = (const float*)d_in[28];

  int N = in_sizes[0] / 16;
  int E = in_sizes[1] / 2;
  const int* srcp = ei;
  const int* dstp = ei + E;
  int EA = E + N;   // CSR entries incl. self-loops
  int NB = (N + 511) / 512;   // scan blocks (<=1024)

  char* wsb = (char*)d_ws;
  size_t off = 0;
  auto alloc = [&](size_t bytes) -> char* {
    char* p = wsb + off;
    off += (bytes + 255) & ~(size_t)255;
    return p;
  };
  int*       cnt     = (int*)alloc((size_t)N * 4);
  int*       row_ptr = (int*)alloc((size_t)(N + 1) * 4);
  int*       fill    = (int*)alloc((size_t)N * 4);
  int*       bpart   = (int*)alloc((size_t)1024 * 4);
  int*       boff    = (int*)alloc((size_t)1024 * 4);
  int*       csr_src = (int*)alloc((size_t)EA * 4);
  _Float16*  ea_csr  = (_Float16*)alloc((size_t)EA * 8 * 2);
  _Float16*  xl      = (_Float16*)alloc((size_t)N * 128 * 2);
  _Float16*  xr      = (_Float16*)alloc((size_t)N * 128 * 2);
  _Float16*  h16     = (_Float16*)alloc((size_t)N * 128 * 2);
  _Float16*  h3      = (_Float16*)alloc((size_t)N * 32 * 2);
  float*     gmean   = (float*)alloc((size_t)GNUM * 32 * 4);
  int*       gstart  = (int*)alloc((size_t)(GNUM + 1) * 4);
  _Float16*  wp2l    = (_Float16*)alloc((size_t)128 * 128 * 2);
  _Float16*  wp2r    = (_Float16*)alloc((size_t)128 * 128 * 2);
  _Float16*  wp3l    = (_Float16*)alloc((size_t)128 * 32 * 2);
  _Float16*  wp3r    = (_Float16*)alloc((size_t)128 * 32 * 2);

  hipMemsetAsync(cnt, 0, (size_t)N * 4, stream);

  hist_kernel<<<(E + 255) / 256, 256, 0, stream>>>(dstp, cnt, E);
  scan_part_kernel<<<NB, 256, 0, stream>>>(cnt, bpart, N);
  scan_top_kernel<<<1, 1024, 0, stream>>>(bpart, boff, row_ptr, NB, N);
  scan_write_kernel<<<NB, 256, 0, stream>>>(cnt, boff, row_ptr, fill, N);
  scatter_kernel<<<(E + 255) / 256, 256, 0, stream>>>(srcp, dstp, eattr, fill, csr_src, ea_csr, E);
  selfloop_kernel<<<(N + 255) / 256, 256, 0, stream>>>(row_ptr, csr_src, ea_csr, N);
  gbound_kernel<<<1, 256, 0, stream>>>(batch, gstart, N);
  // pack MFMA weights: (NC/16)*(K/32)*64 threads each
  pack_kernel<<<dim3(8, 2), 256, 0, stream>>>(wl2, wp2l, wr2, wp2r, 128, 128);
  pack_kernel<<<dim3(2, 2), 256, 0, stream>>>(wl3, wp3l, wr3, wp3r, 128, 32);

  // layer 1: K=16 -> 128 (f32 VALU, cheap)
  k1_kernel<16, 128><<<dim3((N + 63) / 64, 2), 256, 0, stream>>>(
      x, wl1, bl1, xl, wr1, br1, xr, N);
  k2_kernel<4><<<(N + 3) / 4, 128, 0, stream>>>(xl, xr, row_ptr, csr_src, ea_csr,
                                                we1, at1, bc1, h16, N);
  // layer 2: K=128 -> 128 (fp16 MFMA)
  k1m_kernel<128, 128><<<dim3((N + 63) / 64, 2), 256, 0, stream>>>(
      h16, wp2l, bl2, xl, wp2r, br2, xr, N);
  k2_kernel<4><<<(N + 3) / 4, 128, 0, stream>>>(xl, xr, row_ptr, csr_src, ea_csr,
                                                we2, at2, bc2, h16, N);
  // layer 3: K=128 -> 32 (fp16 MFMA, single head)
  k1m_kernel<128, 32><<<dim3((N + 63) / 64, 2), 256, 0, stream>>>(
      h16, wp3l, bl3, xl, wp3r, br3, xr, N);
  k2_kernel<1><<<(N + 15) / 16, 128, 0, stream>>>(xl, xr, row_ptr, csr_src, ea_csr,
                                                  we3, at3, bc3, h3, N);

  pool2_kernel<<<GNUM, 256, 0, stream>>>(h3, gstart, gmean);
  fc_kernel<<<GNUM, 64, 0, stream>>>(gmean, wf1, bf1, wf2, bf2, (float*)d_out);
}

// Round 6
// 775.848 us; speedup vs baseline: 2.5797x; 1.1485x over previous
//
#include <hip/hip_runtime.h>
#include <cstdint>
#include <type_traits>

// GNN GATv2 x3 + mean-pool + MLP.
// fp16 MFMA for the K=128 node-transform GEMMs (weights pre-packed into
// B-fragment order); fp16 feature tables + fp16 CSR-ordered edge features.
// k2 attention inner loop in packed-fp16 VALU (v_pk_fma_f16) — R5 showed it
// VALU-bound at 83% busy with scalar-f32 math.
constexpr int GNUM = 128;   // graphs

typedef _Float16 h2 __attribute__((ext_vector_type(2)));
typedef _Float16 h4 __attribute__((ext_vector_type(4)));
typedef _Float16 h8 __attribute__((ext_vector_type(8)));
typedef float f4 __attribute__((ext_vector_type(4)));

// ---------------------------------------------------------------- setup kernels

__global__ __launch_bounds__(256) void hist_kernel(const int* __restrict__ dst,
                                                   int* __restrict__ cnt, int E) {
  int i = blockIdx.x * 256 + threadIdx.x;
  if (i < E) atomicAdd(&cnt[dst[i]], 1);
}

// ---- 3-phase parallel exclusive scan of (cnt[i]+1), 512 elems per block ----
__global__ __launch_bounds__(256) void scan_part_kernel(const int* __restrict__ cnt,
                                                        int* __restrict__ bpart, int n) {
  __shared__ int red[256];
  int base = blockIdx.x * 512;
  int t = threadIdx.x;
  int s = 0;
  int i0 = base + t, i1 = base + 256 + t;
  if (i0 < n) s += cnt[i0] + 1;
  if (i1 < n) s += cnt[i1] + 1;
  red[t] = s;
  __syncthreads();
  for (int off = 128; off > 0; off >>= 1) {
    if (t < off) red[t] += red[t + off];
    __syncthreads();
  }
  if (t == 0) bpart[blockIdx.x] = red[0];
}

__global__ __launch_bounds__(1024) void scan_top_kernel(const int* __restrict__ bpart,
                                                        int* __restrict__ boff,
                                                        int* __restrict__ row_ptr,
                                                        int B, int n) {
  __shared__ int buf[1024];
  int t = threadIdx.x;
  buf[t] = (t < B) ? bpart[t] : 0;
  __syncthreads();
  for (int off = 1; off < 1024; off <<= 1) {
    int v = (t >= off) ? buf[t - off] : 0;
    __syncthreads();
    buf[t] += v;
    __syncthreads();
  }
  if (t < B) boff[t] = (t == 0) ? 0 : buf[t - 1];
  if (t == 0) row_ptr[n] = buf[1023];
}

__global__ __launch_bounds__(256) void scan_write_kernel(const int* __restrict__ cnt,
                                                         const int* __restrict__ boff,
                                                         int* __restrict__ row_ptr,
                                                         int* __restrict__ fill, int n) {
  __shared__ int red[256];
  int base = blockIdx.x * 512;
  int t = threadIdx.x;
  int i0 = base + 2 * t, i1 = base + 2 * t + 1;
  int v0 = (i0 < n) ? cnt[i0] + 1 : 0;
  int v1 = (i1 < n) ? cnt[i1] + 1 : 0;
  int val = v0 + v1;
  red[t] = val;
  __syncthreads();
  for (int off = 1; off < 256; off <<= 1) {
    int u = (t >= off) ? red[t - off] : 0;
    __syncthreads();
    red[t] += u;
    __syncthreads();
  }
  int o = boff[blockIdx.x] + red[t] - val;   // exclusive prefix for this pair
  if (i0 < n) { row_ptr[i0] = o; fill[i0] = o; }
  if (i1 < n) { row_ptr[i1] = o + v0; fill[i1] = o + v0; }
}

// scatter edges into CSR slots; write fp16 edge features directly in CSR order
__global__ __launch_bounds__(256) void scatter_kernel(const int* __restrict__ src,
                                                      const int* __restrict__ dst,
                                                      const float* __restrict__ ea,
                                                      int* __restrict__ fill,
                                                      int* __restrict__ csr_src,
                                                      _Float16* __restrict__ ea_csr, int E) {
  int i = blockIdx.x * 256 + threadIdx.x;
  if (i >= E) return;
  int d = dst[i];
  int p = atomicAdd(&fill[d], 1);
  csr_src[p] = src[i];
  float4 e0 = *(const float4*)&ea[(size_t)i * 8];
  float4 e1 = *(const float4*)&ea[(size_t)i * 8 + 4];
  h8 v;
  v[0] = (_Float16)e0.x; v[1] = (_Float16)e0.y; v[2] = (_Float16)e0.z; v[3] = (_Float16)e0.w;
  v[4] = (_Float16)e1.x; v[5] = (_Float16)e1.y; v[6] = (_Float16)e1.z; v[7] = (_Float16)e1.w;
  *(h8*)&ea_csr[(size_t)p * 8] = v;
}

// fill the self-loop slot (last of each segment): src=i, feature=mean of segment
__global__ __launch_bounds__(256) void selfloop_kernel(const int* __restrict__ row_ptr,
                                                       int* __restrict__ csr_src,
                                                       _Float16* __restrict__ ea_csr, int n) {
  int i = blockIdx.x * 256 + threadIdx.x;
  if (i >= n) return;
  int s = row_ptr[i], e = row_ptr[i + 1] - 1;   // [s,e) = real edges, e = self slot
  float a[8] = {0, 0, 0, 0, 0, 0, 0, 0};
  for (int j = s; j < e; j++) {
    h8 t = *(const h8*)&ea_csr[(size_t)j * 8];
#pragma unroll
    for (int k = 0; k < 8; k++) a[k] += (float)t[k];
  }
  float inv = 1.f / fmaxf((float)(e - s), 1.f);
  h8 o;
#pragma unroll
  for (int k = 0; k < 8; k++) o[k] = (_Float16)(a[k] * inv);
  *(h8*)&ea_csr[(size_t)e * 8] = o;
  csr_src[e] = i;
}

// pack w [K][NC] f32 -> fp16 MFMA B-fragment order:
// wp[((nt*KB + kb)*64 + lane)*8 + j] = w[kb*32 + (lane>>4)*8 + j][nt*16 + (lane&15)]
__global__ __launch_bounds__(256) void pack_kernel(const float* __restrict__ w0,
                                                   _Float16* __restrict__ wp0,
                                                   const float* __restrict__ w1,
                                                   _Float16* __restrict__ wp1,
                                                   int K, int NC) {
  const float* w = blockIdx.y ? w1 : w0;
  _Float16* wp = blockIdx.y ? wp1 : wp0;
  int KB = K / 32;
  int total = (NC / 16) * KB * 64;
  int idx = blockIdx.x * 256 + threadIdx.x;
  if (idx >= total) return;
  int lane = idx & 63;
  int blk = idx >> 6;
  int nt = blk / KB, kb = blk % KB;
  int col = nt * 16 + (lane & 15);
  int krow = kb * 32 + (lane >> 4) * 8;
  h8 v;
#pragma unroll
  for (int j = 0; j < 8; j++) v[j] = (_Float16)w[(size_t)(krow + j) * NC + col];
  *(h8*)&wp[(size_t)idx * 8] = v;
}

// ---------------------------------------------------------------- node transform GEMMs

// f32 VALU path for layer 1 (K=16, tiny): out = x@w + b, fp16 output
template <int K, int NCOLS>
__global__ __launch_bounds__(256) void k1_kernel(const float* __restrict__ x,
                                                 const float* __restrict__ w0,
                                                 const float* __restrict__ b0,
                                                 _Float16* __restrict__ out0,
                                                 const float* __restrict__ w1,
                                                 const float* __restrict__ b1,
                                                 _Float16* __restrict__ out1, int n) {
  constexpr int KC = (K < 32) ? K : 32;
  constexpr int CG = NCOLS / 4;
  constexpr int NG = 256 / CG;
  constexpr int MTILE = NG * 8;
  constexpr int XS = KC + 4;
  __shared__ float xs[MTILE * XS];
  __shared__ float ws[KC * NCOLS];

  const float* w = blockIdx.y ? w1 : w0;
  const float* b = blockIdx.y ? b1 : b0;
  _Float16* out = blockIdx.y ? out1 : out0;

  int tid = threadIdx.x;
  int cg = tid % CG, ng = tid / CG;
  int c0 = 4 * cg, n0 = 8 * ng;
  int node0 = blockIdx.x * MTILE;

  float acc[8][4] = {};

  for (int k0 = 0; k0 < K; k0 += KC) {
    for (int idx = tid; idx < MTILE * KC / 4; idx += 256) {
      int nl = idx / (KC / 4), kq = idx % (KC / 4);
      int gn = node0 + nl;
      float4 v = make_float4(0.f, 0.f, 0.f, 0.f);
      if (gn < n) v = *(const float4*)&x[(size_t)gn * K + k0 + 4 * kq];
      *(float4*)&xs[nl * XS + 4 * kq] = v;
    }
    for (int idx = tid; idx < KC * NCOLS / 4; idx += 256) {
      int kr = idx / (NCOLS / 4), cq = idx % (NCOLS / 4);
      *(float4*)&ws[kr * NCOLS + 4 * cq] =
          *(const float4*)&w[(size_t)(k0 + kr) * NCOLS + 4 * cq];
    }
    __syncthreads();
#pragma unroll
    for (int kk = 0; kk < KC; kk += 4) {
      float4 wv0 = *(const float4*)&ws[(kk + 0) * NCOLS + c0];
      float4 wv1 = *(const float4*)&ws[(kk + 1) * NCOLS + c0];
      float4 wv2 = *(const float4*)&ws[(kk + 2) * NCOLS + c0];
      float4 wv3 = *(const float4*)&ws[(kk + 3) * NCOLS + c0];
#pragma unroll
      for (int j = 0; j < 8; j++) {
        float4 xv = *(const float4*)&xs[(n0 + j) * XS + kk];
        acc[j][0] += xv.x * wv0.x + xv.y * wv1.x + xv.z * wv2.x + xv.w * wv3.x;
        acc[j][1] += xv.x * wv0.y + xv.y * wv1.y + xv.z * wv2.y + xv.w * wv3.y;
        acc[j][2] += xv.x * wv0.z + xv.y * wv1.z + xv.z * wv2.z + xv.w * wv3.z;
        acc[j][3] += xv.x * wv0.w + xv.y * wv1.w + xv.z * wv2.w + xv.w * wv3.w;
      }
    }
    __syncthreads();
  }

  float4 bv = *(const float4*)&b[c0];
#pragma unroll
  for (int j = 0; j < 8; j++) {
    int gn = node0 + n0 + j;
    if (gn < n) {
      h4 o;
      o[0] = (_Float16)(acc[j][0] + bv.x);
      o[1] = (_Float16)(acc[j][1] + bv.y);
      o[2] = (_Float16)(acc[j][2] + bv.z);
      o[3] = (_Float16)(acc[j][3] + bv.w);
      *(h4*)&out[(size_t)gn * NCOLS + c0] = o;
    }
  }
}

// fp16 MFMA path for K=128 GEMMs. x fp16 [n,K]; wp pre-packed B-fragments;
// out fp16 [n,NCOLS]. 256 thr = 4 waves, 16 nodes/wave, 64 nodes/block.
template <int K, int NCOLS>
__global__ __launch_bounds__(256) void k1m_kernel(const _Float16* __restrict__ x,
                                                  const _Float16* __restrict__ wp0,
                                                  const float* __restrict__ b0,
                                                  _Float16* __restrict__ out0,
                                                  const _Float16* __restrict__ wp1,
                                                  const float* __restrict__ b1,
                                                  _Float16* __restrict__ out1, int n) {
  constexpr int NT = NCOLS / 16, KB = K / 32;
  const _Float16* wp = blockIdx.y ? wp1 : wp0;
  const float* b = blockIdx.y ? b1 : b0;
  _Float16* out = blockIdx.y ? out1 : out0;

  int tid = threadIdx.x;
  int wave = tid >> 6, lane = tid & 63;
  int m = lane & 15, quad = lane >> 4;
  int node0 = blockIdx.x * 64 + wave * 16;

  // A fragments: A[m=lane&15][k=quad*8+j], one 16B load per k-block
  h8 afrag[KB];
  int anode = node0 + m;
  if (anode < n) {
#pragma unroll
    for (int kb = 0; kb < KB; kb++)
      afrag[kb] = *(const h8*)&x[(size_t)anode * K + kb * 32 + quad * 8];
  } else {
#pragma unroll
    for (int kb = 0; kb < KB; kb++) afrag[kb] = (h8)(_Float16)0.f;
  }

  f4 acc[NT] = {};
#pragma unroll
  for (int nt = 0; nt < NT; nt++) {
#pragma unroll
    for (int kb = 0; kb < KB; kb++) {
      h8 bfrag = *(const h8*)&wp[((size_t)(nt * KB + kb) * 64 + lane) * 8];
      acc[nt] = __builtin_amdgcn_mfma_f32_16x16x32_f16(afrag[kb], bfrag, acc[nt], 0, 0, 0);
    }
  }

  // C/D: col=lane&15, row=quad*4+reg
#pragma unroll
  for (int nt = 0; nt < NT; nt++) {
#pragma unroll
    for (int r = 0; r < 4; r++) {
      int row = node0 + quad * 4 + r;
      if (row < n) {
        int col = nt * 16 + m;
        out[(size_t)row * NCOLS + col] = (_Float16)(acc[nt][r] + b[col]);
      }
    }
  }
}

// ---------------------------------------------------------------- fused GATv2 edge+softmax+aggregate
// One-pass softmax (no max-shift; logits O(1)). Self-loop is a normal CSR entry.
// 8 lanes per head, 4 channels per lane. Inner math in packed fp16 (v_pk_*);
// att pre-scaled by log2(e) so the softmax exp is a bare v_exp_f32.
template <int H>
__global__ __launch_bounds__(128) void k2_kernel(
    const _Float16* __restrict__ xl, const _Float16* __restrict__ xr,
    const int* __restrict__ row_ptr, const int* __restrict__ csr_src,
    const _Float16* __restrict__ ea_csr, const float* __restrict__ we,
    const float* __restrict__ att, const float* __restrict__ bc,
    _Float16* __restrict__ out, int n) {
  constexpr int HC = H * 32;
  constexpr int NL = HC / 4;   // lanes per node (32 or 8)
  constexpr int NPB = 128 / NL;

  int tid = threadIdx.x;
  int ln = tid / NL, q = tid % NL;
  int c0 = 4 * q;
  int node = blockIdx.x * NPB + ln;
  if (node >= n) return;

  // per-thread slice of we (8 x 4ch) as fp16 pairs, att scaled by log2(e)
  h2 w2[8][2];
#pragma unroll
  for (int k = 0; k < 8; k++) {
    float4 v = *(const float4*)&we[k * HC + c0];
    w2[k][0] = h2{(_Float16)v.x, (_Float16)v.y};
    w2[k][1] = h2{(_Float16)v.z, (_Float16)v.w};
  }
  const float LOG2E = 1.44269504088896f;
  float4 av = *(const float4*)&att[c0];
  h2 a0 = h2{(_Float16)(av.x * LOG2E), (_Float16)(av.y * LOG2E)};
  h2 a1 = h2{(_Float16)(av.z * LOG2E), (_Float16)(av.w * LOG2E)};
  h4 xrh = *(const h4*)&xr[(size_t)node * HC + c0];
  h2 xr0 = h2{xrh[0], xrh[1]}, xr1 = h2{xrh[2], xrh[3]};
  const h2 p2 = h2{(_Float16)0.2f, (_Float16)0.2f};

  float acc[4] = {0.f, 0.f, 0.f, 0.f};
  float s = 0.f;

  int start = row_ptr[node], end = row_ptr[node + 1];
  for (int j = start; j < end; j++) {
    int src = csr_src[j];
    h8 eh = *(const h8*)&ea_csr[(size_t)j * 8];
    h4 xlh = *(const h4*)&xl[(size_t)src * HC + c0];

    h2 t0 = h2{xlh[0], xlh[1]} + xr0;
    h2 t1 = h2{xlh[2], xlh[3]} + xr1;
#pragma unroll
    for (int k = 0; k < 8; k++) {
      h2 ev = h2{eh[k], eh[k]};
      t0 += ev * w2[k][0];
      t1 += ev * w2[k][1];
    }
    // leaky_relu(t, 0.2) in packed fp16
    t0 = __builtin_elementwise_max(t0, t0 * p2);
    t1 = __builtin_elementwise_max(t1, t1 * p2);
    // att dot (already scaled by log2e)
    h2 pd = t0 * a0 + t1 * a1;
    float part = (float)pd[0] + (float)pd[1];
    part += __shfl_xor(part, 1, 64);
    part += __shfl_xor(part, 2, 64);
    part += __shfl_xor(part, 4, 64);
    float p = __builtin_amdgcn_exp2f(part);
    s += p;
#pragma unroll
    for (int i = 0; i < 4; i++) acc[i] += p * (float)xlh[i];
  }

  float inv = 1.f / (s + 1e-16f);
  h4 o;
#pragma unroll
  for (int i = 0; i < 4; i++) {
    float v = acc[i] * inv + bc[c0 + i];
    o[i] = (_Float16)(v > 0.f ? v : (__expf(v) - 1.f));   // elu
  }
  *(h4*)&out[(size_t)node * HC + c0] = o;
}

// ---------------------------------------------------------------- pooling + MLP

__global__ __launch_bounds__(256) void gbound_kernel(const int* __restrict__ batch,
                                                     int* __restrict__ gstart, int n) {
  int g = blockIdx.x * 256 + threadIdx.x;
  if (g > GNUM) return;
  int lo = 0, hi = n;
  while (lo < hi) {
    int mid = (lo + hi) >> 1;
    if (batch[mid] < g) lo = mid + 1; else hi = mid;
  }
  gstart[g] = lo;
}

__global__ __launch_bounds__(256) void pool2_kernel(const _Float16* __restrict__ h,
                                                    const int* __restrict__ gstart,
                                                    float* __restrict__ gmean) {
  __shared__ float red[256];
  int g = blockIdx.x;
  int t = threadIdx.x;
  int s = gstart[g], e = gstart[g + 1];
  int c = t & 31, rg = t >> 5;
  float acc = 0.f;
  for (int i = s + rg; i < e; i += 8) acc += (float)h[(size_t)i * 32 + c];
  red[t] = acc;
  __syncthreads();
  if (t < 128) red[t] += red[t + 128];
  __syncthreads();
  if (t < 64) red[t] += red[t + 64];
  __syncthreads();
  if (t < 32) {
    float v = red[t] + red[t + 32];
    gmean[g * 32 + t] = v / fmaxf((float)(e - s), 1.f);
  }
}

__global__ __launch_bounds__(64) void fc_kernel(const float* __restrict__ gmean,
                                                const float* __restrict__ w1,
                                                const float* __restrict__ b1,
                                                const float* __restrict__ w2,
                                                const float* __restrict__ b2,
                                                float* __restrict__ out) {
  __shared__ float g[32];
  __shared__ float a1[64];
  int gi = blockIdx.x;
  int t = threadIdx.x;
  if (t < 32) g[t] = gmean[gi * 32 + t];
  __syncthreads();
  float v = b1[t];
  for (int k = 0; k < 32; k++) v += g[k] * w1[k * 64 + t];
  a1[t] = v > 0.f ? v : (__expf(v) - 1.f);
  __syncthreads();
  if (t < 4) {
    float o = b2[t];
    for (int k = 0; k < 64; k++) o += a1[k] * w2[k * 4 + t];
    out[gi * 4 + t] = o;
  }
}

// ---------------------------------------------------------------- launch

extern "C" void kernel_launch(void* const* d_in, const int* in_sizes, int n_in,
                              void* d_out, int out_size, void* d_ws, size_t ws_size,
                              hipStream_t stream) {
  const float* x     = (const float*)d_in[0];
  const int*   ei    = (const int*)d_in[1];
  const float* eattr = (const float*)d_in[2];
  const int*   batch = (const int*)d_in[3];
  const float *wl1 = (const float*)d_in[4],  *bl1 = (const float*)d_in[5];
  const float *wr1 = (const float*)d_in[6],  *br1 = (const float*)d_in[7];
  const float *we1 = (const float*)d_in[8],  *at1 = (const float*)d_in[9];
  const float *bc1 = (const float*)d_in[10];
  const float *wl2 = (const float*)d_in[11], *bl2 = (const float*)d_in[12];
  const float *wr2 = (const float*)d_in[13], *br2 = (const float*)d_in[14];
  const float *we2 = (const float*)d_in[15], *at2 = (const float*)d_in[16];
  const float *bc2 = (const float*)d_in[17];
  const float *wl3 = (const float*)d_in[18], *bl3 = (const float*)d_in[19];
  const float *wr3 = (const float*)d_in[20], *br3 = (const float*)d_in[21];
  const float *we3 = (const float*)d_in[22], *at3 = (const float*)d_in[23];
  const float *bc3 = (const float*)d_in[24];
  const float *wf1 = (const float*)d_in[25], *bf1 = (const float*)d_in[26];
  const float *wf2 = (const float*)d_in[27], *bf2 = (const float*)d_in[28];

  int N = in_sizes[0] / 16;
  int E = in_sizes[1] / 2;
  const int* srcp = ei;
  const int* dstp = ei + E;
  int EA = E + N;   // CSR entries incl. self-loops
  int NB = (N + 511) / 512;   // scan blocks (<=1024)

  char* wsb = (char*)d_ws;
  size_t off = 0;
  auto alloc = [&](size_t bytes) -> char* {
    char* p = wsb + off;
    off += (bytes + 255) & ~(size_t)255;
    return p;
  };
  int*       cnt     = (int*)alloc((size_t)N * 4);
  int*       row_ptr = (int*)alloc((size_t)(N + 1) * 4);
  int*       fill    = (int*)alloc((size_t)N * 4);
  int*       bpart   = (int*)alloc((size_t)1024 * 4);
  int*       boff    = (int*)alloc((size_t)1024 * 4);
  int*       csr_src = (int*)alloc((size_t)EA * 4);
  _Float16*  ea_csr  = (_Float16*)alloc((size_t)EA * 8 * 2);
  _Float16*  xl      = (_Float16*)alloc((size_t)N * 128 * 2);
  _Float16*  xr      = (_Float16*)alloc((size_t)N * 128 * 2);
  _Float16*  h16     = (_Float16*)alloc((size_t)N * 128 * 2);
  _Float16*  h3      = (_Float16*)alloc((size_t)N * 32 * 2);
  float*     gmean   = (float*)alloc((size_t)GNUM * 32 * 4);
  int*       gstart  = (int*)alloc((size_t)(GNUM + 1) * 4);
  _Float16*  wp2l    = (_Float16*)alloc((size_t)128 * 128 * 2);
  _Float16*  wp2r    = (_Float16*)alloc((size_t)128 * 128 * 2);
  _Float16*  wp3l    = (_Float16*)alloc((size_t)128 * 32 * 2);
  _Float16*  wp3r    = (_Float16*)alloc((size_t)128 * 32 * 2);

  hipMemsetAsync(cnt, 0, (size_t)N * 4, stream);

  hist_kernel<<<(E + 255) / 256, 256, 0, stream>>>(dstp, cnt, E);
  scan_part_kernel<<<NB, 256, 0, stream>>>(cnt, bpart, N);
  scan_top_kernel<<<1, 1024, 0, stream>>>(bpart, boff, row_ptr, NB, N);
  scan_write_kernel<<<NB, 256, 0, stream>>>(cnt, boff, row_ptr, fill, N);
  scatter_kernel<<<(E + 255) / 256, 256, 0, stream>>>(srcp, dstp, eattr, fill, csr_src, ea_csr, E);
  selfloop_kernel<<<(N + 255) / 256, 256, 0, stream>>>(row_ptr, csr_src, ea_csr, N);
  gbound_kernel<<<1, 256, 0, stream>>>(batch, gstart, N);
  // pack MFMA weights: (NC/16)*(K/32)*64 threads each
  pack_kernel<<<dim3(8, 2), 256, 0, stream>>>(wl2, wp2l, wr2, wp2r, 128, 128);
  pack_kernel<<<dim3(2, 2), 256, 0, stream>>>(wl3, wp3l, wr3, wp3r, 128, 32);

  // layer 1: K=16 -> 128 (f32 VALU, cheap)
  k1_kernel<16, 128><<<dim3((N + 63) / 64, 2), 256, 0, stream>>>(
      x, wl1, bl1, xl, wr1, br1, xr, N);
  k2_kernel<4><<<(N + 3) / 4, 128, 0, stream>>>(xl, xr, row_ptr, csr_src, ea_csr,
                                                we1, at1, bc1, h16, N);
  // layer 2: K=128 -> 128 (fp16 MFMA)
  k1m_kernel<128, 128><<<dim3((N + 63) / 64, 2), 256, 0, stream>>>(
      h16, wp2l, bl2, xl, wp2r, br2, xr, N);
  k2_kernel<4><<<(N + 3) / 4, 128, 0, stream>>>(xl, xr, row_ptr, csr_src, ea_csr,
                                                we2, at2, bc2, h16, N);
  // layer 3: K=128 -> 32 (fp16 MFMA, single head)
  k1m_kernel<128, 32><<<dim3((N + 63) / 64, 2), 256, 0, stream>>>(
      h16, wp3l, bl3, xl, wp3r, br3, xr, N);
  k2_kernel<1><<<(N + 15) / 16, 128, 0, stream>>>(xl, xr, row_ptr, csr_src, ea_csr,
                                                  we3, at3, bc3, h3, N);

  pool2_kernel<<<GNUM, 256, 0, stream>>>(h3, gstart, gmean);
  fc_kernel<<<GNUM, 64, 0, stream>>>(gmean, wf1, bf1, wf2, bf2, (float*)d_out);
}

// Round 7
// 712.806 us; speedup vs baseline: 2.8079x; 1.0884x over previous
//
#include <hip/hip_runtime.h>
#include <cstdint>
#include <type_traits>

// GNN GATv2 x3 + mean-pool + MLP.
// fp16 MFMA K=128 GEMMs; fp16 tables; CSR-ordered fp16 edge features.
// k2: packed-fp16 logit math + 2-edge software pipeline (R6: latency-bound,
// VALUBusy 56% — next pair's gathers now overlap current pair's shfl/exp).
constexpr int GNUM = 128;   // graphs

typedef _Float16 h2 __attribute__((ext_vector_type(2)));
typedef _Float16 h4 __attribute__((ext_vector_type(4)));
typedef _Float16 h8 __attribute__((ext_vector_type(8)));
typedef float f4 __attribute__((ext_vector_type(4)));

// ---------------------------------------------------------------- setup kernels

__global__ __launch_bounds__(256) void hist_kernel(const int* __restrict__ dst,
                                                   int* __restrict__ cnt, int E) {
  int i = blockIdx.x * 256 + threadIdx.x;
  if (i < E) atomicAdd(&cnt[dst[i]], 1);
}

// ---- 3-phase parallel exclusive scan of (cnt[i]+1), 512 elems per block ----
__global__ __launch_bounds__(256) void scan_part_kernel(const int* __restrict__ cnt,
                                                        int* __restrict__ bpart, int n) {
  __shared__ int red[256];
  int base = blockIdx.x * 512;
  int t = threadIdx.x;
  int s = 0;
  int i0 = base + t, i1 = base + 256 + t;
  if (i0 < n) s += cnt[i0] + 1;
  if (i1 < n) s += cnt[i1] + 1;
  red[t] = s;
  __syncthreads();
  for (int off = 128; off > 0; off >>= 1) {
    if (t < off) red[t] += red[t + off];
    __syncthreads();
  }
  if (t == 0) bpart[blockIdx.x] = red[0];
}

__global__ __launch_bounds__(1024) void scan_top_kernel(const int* __restrict__ bpart,
                                                        int* __restrict__ boff,
                                                        int* __restrict__ row_ptr,
                                                        int B, int n) {
  __shared__ int buf[1024];
  int t = threadIdx.x;
  buf[t] = (t < B) ? bpart[t] : 0;
  __syncthreads();
  for (int off = 1; off < 1024; off <<= 1) {
    int v = (t >= off) ? buf[t - off] : 0;
    __syncthreads();
    buf[t] += v;
    __syncthreads();
  }
  if (t < B) boff[t] = (t == 0) ? 0 : buf[t - 1];
  if (t == 0) row_ptr[n] = buf[1023];
}

__global__ __launch_bounds__(256) void scan_write_kernel(const int* __restrict__ cnt,
                                                         const int* __restrict__ boff,
                                                         int* __restrict__ row_ptr,
                                                         int* __restrict__ fill, int n) {
  __shared__ int red[256];
  int base = blockIdx.x * 512;
  int t = threadIdx.x;
  int i0 = base + 2 * t, i1 = base + 2 * t + 1;
  int v0 = (i0 < n) ? cnt[i0] + 1 : 0;
  int v1 = (i1 < n) ? cnt[i1] + 1 : 0;
  int val = v0 + v1;
  red[t] = val;
  __syncthreads();
  for (int off = 1; off < 256; off <<= 1) {
    int u = (t >= off) ? red[t - off] : 0;
    __syncthreads();
    red[t] += u;
    __syncthreads();
  }
  int o = boff[blockIdx.x] + red[t] - val;   // exclusive prefix for this pair
  if (i0 < n) { row_ptr[i0] = o; fill[i0] = o; }
  if (i1 < n) { row_ptr[i1] = o + v0; fill[i1] = o + v0; }
}

// scatter edges into CSR slots; write fp16 edge features directly in CSR order
__global__ __launch_bounds__(256) void scatter_kernel(const int* __restrict__ src,
                                                      const int* __restrict__ dst,
                                                      const float* __restrict__ ea,
                                                      int* __restrict__ fill,
                                                      int* __restrict__ csr_src,
                                                      _Float16* __restrict__ ea_csr, int E) {
  int i = blockIdx.x * 256 + threadIdx.x;
  if (i >= E) return;
  int d = dst[i];
  int p = atomicAdd(&fill[d], 1);
  csr_src[p] = src[i];
  float4 e0 = *(const float4*)&ea[(size_t)i * 8];
  float4 e1 = *(const float4*)&ea[(size_t)i * 8 + 4];
  h8 v;
  v[0] = (_Float16)e0.x; v[1] = (_Float16)e0.y; v[2] = (_Float16)e0.z; v[3] = (_Float16)e0.w;
  v[4] = (_Float16)e1.x; v[5] = (_Float16)e1.y; v[6] = (_Float16)e1.z; v[7] = (_Float16)e1.w;
  *(h8*)&ea_csr[(size_t)p * 8] = v;
}

// fill the self-loop slot (last of each segment): src=i, feature=mean of segment
__global__ __launch_bounds__(256) void selfloop_kernel(const int* __restrict__ row_ptr,
                                                       int* __restrict__ csr_src,
                                                       _Float16* __restrict__ ea_csr, int n) {
  int i = blockIdx.x * 256 + threadIdx.x;
  if (i >= n) return;
  int s = row_ptr[i], e = row_ptr[i + 1] - 1;   // [s,e) = real edges, e = self slot
  float a[8] = {0, 0, 0, 0, 0, 0, 0, 0};
  for (int j = s; j < e; j++) {
    h8 t = *(const h8*)&ea_csr[(size_t)j * 8];
#pragma unroll
    for (int k = 0; k < 8; k++) a[k] += (float)t[k];
  }
  float inv = 1.f / fmaxf((float)(e - s), 1.f);
  h8 o;
#pragma unroll
  for (int k = 0; k < 8; k++) o[k] = (_Float16)(a[k] * inv);
  *(h8*)&ea_csr[(size_t)e * 8] = o;
  csr_src[e] = i;
}

// pack w [K][NC] f32 -> fp16 MFMA B-fragment order
__global__ __launch_bounds__(256) void pack_kernel(const float* __restrict__ w0,
                                                   _Float16* __restrict__ wp0,
                                                   const float* __restrict__ w1,
                                                   _Float16* __restrict__ wp1,
                                                   int K, int NC) {
  const float* w = blockIdx.y ? w1 : w0;
  _Float16* wp = blockIdx.y ? wp1 : wp0;
  int KB = K / 32;
  int total = (NC / 16) * KB * 64;
  int idx = blockIdx.x * 256 + threadIdx.x;
  if (idx >= total) return;
  int lane = idx & 63;
  int blk = idx >> 6;
  int nt = blk / KB, kb = blk % KB;
  int col = nt * 16 + (lane & 15);
  int krow = kb * 32 + (lane >> 4) * 8;
  h8 v;
#pragma unroll
  for (int j = 0; j < 8; j++) v[j] = (_Float16)w[(size_t)(krow + j) * NC + col];
  *(h8*)&wp[(size_t)idx * 8] = v;
}

// ---------------------------------------------------------------- node transform GEMMs

// f32 VALU path for layer 1 (K=16, tiny): out = x@w + b, fp16 output
template <int K, int NCOLS>
__global__ __launch_bounds__(256) void k1_kernel(const float* __restrict__ x,
                                                 const float* __restrict__ w0,
                                                 const float* __restrict__ b0,
                                                 _Float16* __restrict__ out0,
                                                 const float* __restrict__ w1,
                                                 const float* __restrict__ b1,
                                                 _Float16* __restrict__ out1, int n) {
  constexpr int KC = (K < 32) ? K : 32;
  constexpr int CG = NCOLS / 4;
  constexpr int NG = 256 / CG;
  constexpr int MTILE = NG * 8;
  constexpr int XS = KC + 4;
  __shared__ float xs[MTILE * XS];
  __shared__ float ws[KC * NCOLS];

  const float* w = blockIdx.y ? w1 : w0;
  const float* b = blockIdx.y ? b1 : b0;
  _Float16* out = blockIdx.y ? out1 : out0;

  int tid = threadIdx.x;
  int cg = tid % CG, ng = tid / CG;
  int c0 = 4 * cg, n0 = 8 * ng;
  int node0 = blockIdx.x * MTILE;

  float acc[8][4] = {};

  for (int k0 = 0; k0 < K; k0 += KC) {
    for (int idx = tid; idx < MTILE * KC / 4; idx += 256) {
      int nl = idx / (KC / 4), kq = idx % (KC / 4);
      int gn = node0 + nl;
      float4 v = make_float4(0.f, 0.f, 0.f, 0.f);
      if (gn < n) v = *(const float4*)&x[(size_t)gn * K + k0 + 4 * kq];
      *(float4*)&xs[nl * XS + 4 * kq] = v;
    }
    for (int idx = tid; idx < KC * NCOLS / 4; idx += 256) {
      int kr = idx / (NCOLS / 4), cq = idx % (NCOLS / 4);
      *(float4*)&ws[kr * NCOLS + 4 * cq] =
          *(const float4*)&w[(size_t)(k0 + kr) * NCOLS + 4 * cq];
    }
    __syncthreads();
#pragma unroll
    for (int kk = 0; kk < KC; kk += 4) {
      float4 wv0 = *(const float4*)&ws[(kk + 0) * NCOLS + c0];
      float4 wv1 = *(const float4*)&ws[(kk + 1) * NCOLS + c0];
      float4 wv2 = *(const float4*)&ws[(kk + 2) * NCOLS + c0];
      float4 wv3 = *(const float4*)&ws[(kk + 3) * NCOLS + c0];
#pragma unroll
      for (int j = 0; j < 8; j++) {
        float4 xv = *(const float4*)&xs[(n0 + j) * XS + kk];
        acc[j][0] += xv.x * wv0.x + xv.y * wv1.x + xv.z * wv2.x + xv.w * wv3.x;
        acc[j][1] += xv.x * wv0.y + xv.y * wv1.y + xv.z * wv2.y + xv.w * wv3.y;
        acc[j][2] += xv.x * wv0.z + xv.y * wv1.z + xv.z * wv2.z + xv.w * wv3.z;
        acc[j][3] += xv.x * wv0.w + xv.y * wv1.w + xv.z * wv2.w + xv.w * wv3.w;
      }
    }
    __syncthreads();
  }

  float4 bv = *(const float4*)&b[c0];
#pragma unroll
  for (int j = 0; j < 8; j++) {
    int gn = node0 + n0 + j;
    if (gn < n) {
      h4 o;
      o[0] = (_Float16)(acc[j][0] + bv.x);
      o[1] = (_Float16)(acc[j][1] + bv.y);
      o[2] = (_Float16)(acc[j][2] + bv.z);
      o[3] = (_Float16)(acc[j][3] + bv.w);
      *(h4*)&out[(size_t)gn * NCOLS + c0] = o;
    }
  }
}

// fp16 MFMA path for K=128 GEMMs. 256 thr = 4 waves, 16 nodes/wave.
template <int K, int NCOLS>
__global__ __launch_bounds__(256) void k1m_kernel(const _Float16* __restrict__ x,
                                                  const _Float16* __restrict__ wp0,
                                                  const float* __restrict__ b0,
                                                  _Float16* __restrict__ out0,
                                                  const _Float16* __restrict__ wp1,
                                                  const float* __restrict__ b1,
                                                  _Float16* __restrict__ out1, int n) {
  constexpr int NT = NCOLS / 16, KB = K / 32;
  const _Float16* wp = blockIdx.y ? wp1 : wp0;
  const float* b = blockIdx.y ? b1 : b0;
  _Float16* out = blockIdx.y ? out1 : out0;

  int tid = threadIdx.x;
  int wave = tid >> 6, lane = tid & 63;
  int m = lane & 15, quad = lane >> 4;
  int node0 = blockIdx.x * 64 + wave * 16;

  h8 afrag[KB];
  int anode = node0 + m;
  if (anode < n) {
#pragma unroll
    for (int kb = 0; kb < KB; kb++)
      afrag[kb] = *(const h8*)&x[(size_t)anode * K + kb * 32 + quad * 8];
  } else {
#pragma unroll
    for (int kb = 0; kb < KB; kb++) afrag[kb] = (h8)(_Float16)0.f;
  }

  f4 acc[NT] = {};
#pragma unroll
  for (int nt = 0; nt < NT; nt++) {
#pragma unroll
    for (int kb = 0; kb < KB; kb++) {
      h8 bfrag = *(const h8*)&wp[((size_t)(nt * KB + kb) * 64 + lane) * 8];
      acc[nt] = __builtin_amdgcn_mfma_f32_16x16x32_f16(afrag[kb], bfrag, acc[nt], 0, 0, 0);
    }
  }

#pragma unroll
  for (int nt = 0; nt < NT; nt++) {
#pragma unroll
    for (int r = 0; r < 4; r++) {
      int row = node0 + quad * 4 + r;
      if (row < n) {
        int col = nt * 16 + m;
        out[(size_t)row * NCOLS + col] = (_Float16)(acc[nt][r] + b[col]);
      }
    }
  }
}

// ---------------------------------------------------------------- fused GATv2 edge+softmax+aggregate
// One-pass softmax (no max-shift; logits O(1)). Self-loop is a normal CSR entry
// (so every segment has len >= 1). Packed-fp16 logit math; att pre-scaled by
// log2(e). 2-edge software pipeline: next pair's src/ea loads issue before the
// current pair's shfl-reduce, next xl gathers after the logit math; branch-free
// tail via index clamp + 0-mask.
template <int H>
__global__ __launch_bounds__(128) void k2_kernel(
    const _Float16* __restrict__ xl, const _Float16* __restrict__ xr,
    const int* __restrict__ row_ptr, const int* __restrict__ csr_src,
    const _Float16* __restrict__ ea_csr, const float* __restrict__ we,
    const float* __restrict__ att, const float* __restrict__ bc,
    _Float16* __restrict__ out, int n) {
  constexpr int HC = H * 32;
  constexpr int NL = HC / 4;   // lanes per node (32 or 8)
  constexpr int NPB = 128 / NL;

  int tid = threadIdx.x;
  int ln = tid / NL, q = tid % NL;
  int c0 = 4 * q;
  int node = blockIdx.x * NPB + ln;
  if (node >= n) return;

  // per-thread slice of we (8 x 4ch) as fp16 pairs, att scaled by log2(e)
  h2 w2[8][2];
#pragma unroll
  for (int k = 0; k < 8; k++) {
    float4 v = *(const float4*)&we[k * HC + c0];
    w2[k][0] = h2{(_Float16)v.x, (_Float16)v.y};
    w2[k][1] = h2{(_Float16)v.z, (_Float16)v.w};
  }
  const float LOG2E = 1.44269504088896f;
  float4 av = *(const float4*)&att[c0];
  h2 a0 = h2{(_Float16)(av.x * LOG2E), (_Float16)(av.y * LOG2E)};
  h2 a1 = h2{(_Float16)(av.z * LOG2E), (_Float16)(av.w * LOG2E)};
  h4 xrh = *(const h4*)&xr[(size_t)node * HC + c0];
  h2 xr0 = h2{xrh[0], xrh[1]}, xr1 = h2{xrh[2], xrh[3]};
  const h2 p2 = h2{(_Float16)0.2f, (_Float16)0.2f};

  float acc[4] = {0.f, 0.f, 0.f, 0.f};
  float s = 0.f;

  int start = row_ptr[node], end = row_ptr[node + 1];   // len >= 1 (self loop)
  int len = end - start;
  int pairs = (len + 1) >> 1;

  // prologue: load pair 0 (clamped)
  int j1 = (start + 1 < end) ? start + 1 : start;
  float m1 = (start + 1 < end) ? 1.f : 0.f;
  int s0 = csr_src[start], s1 = csr_src[j1];
  h8 e0 = *(const h8*)&ea_csr[(size_t)start * 8];
  h8 e1 = *(const h8*)&ea_csr[(size_t)j1 * 8];
  h4 x0 = *(const h4*)&xl[(size_t)s0 * HC + c0];
  h4 x1 = *(const h4*)&xl[(size_t)s1 * HC + c0];

  for (int p = 0; p < pairs; p++) {
    // ---- issue next pair's src/ea loads (clamped; unused garbage on last) ----
    int jn = start + 2 * (p + 1);
    int k0 = (jn < end) ? jn : start;
    int k1 = (jn + 1 < end) ? jn + 1 : k0;
    float nm1 = (jn + 1 < end) ? 1.f : 0.f;
    int ns0 = csr_src[k0], ns1 = csr_src[k1];
    h8 ne0 = *(const h8*)&ea_csr[(size_t)k0 * 8];
    h8 ne1 = *(const h8*)&ea_csr[(size_t)k1 * 8];

    // ---- logits for current pair (two independent chains) ----
    h2 t00 = h2{x0[0], x0[1]} + xr0;
    h2 t01 = h2{x0[2], x0[3]} + xr1;
    h2 t10 = h2{x1[0], x1[1]} + xr0;
    h2 t11 = h2{x1[2], x1[3]} + xr1;
#pragma unroll
    for (int k = 0; k < 8; k++) {
      h2 ev0 = h2{e0[k], e0[k]};
      h2 ev1 = h2{e1[k], e1[k]};
      t00 += ev0 * w2[k][0];
      t01 += ev0 * w2[k][1];
      t10 += ev1 * w2[k][0];
      t11 += ev1 * w2[k][1];
    }
    t00 = __builtin_elementwise_max(t00, t00 * p2);
    t01 = __builtin_elementwise_max(t01, t01 * p2);
    t10 = __builtin_elementwise_max(t10, t10 * p2);
    t11 = __builtin_elementwise_max(t11, t11 * p2);
    h2 pd0 = t00 * a0 + t01 * a1;
    h2 pd1 = t10 * a0 + t11 * a1;
    float part0 = (float)pd0[0] + (float)pd0[1];
    float part1 = (float)pd1[0] + (float)pd1[1];

    // ---- issue next pair's xl gathers before the reduce chain ----
    h4 nx0 = *(const h4*)&xl[(size_t)ns0 * HC + c0];
    h4 nx1 = *(const h4*)&xl[(size_t)ns1 * HC + c0];

    // ---- reduce across the 8 lanes of each head, exp, accumulate ----
    part0 += __shfl_xor(part0, 1, 64);
    part1 += __shfl_xor(part1, 1, 64);
    part0 += __shfl_xor(part0, 2, 64);
    part1 += __shfl_xor(part1, 2, 64);
    part0 += __shfl_xor(part0, 4, 64);
    part1 += __shfl_xor(part1, 4, 64);
    float pe0 = __builtin_amdgcn_exp2f(part0);
    float pe1 = __builtin_amdgcn_exp2f(part1) * m1;
    s += pe0 + pe1;
#pragma unroll
    for (int i = 0; i < 4; i++)
      acc[i] += pe0 * (float)x0[i] + pe1 * (float)x1[i];

    // ---- rotate pipeline registers ----
    s0 = ns0; s1 = ns1; e0 = ne0; e1 = ne1; x0 = nx0; x1 = nx1; m1 = nm1;
  }

  float inv = 1.f / (s + 1e-16f);
  h4 o;
#pragma unroll
  for (int i = 0; i < 4; i++) {
    float v = acc[i] * inv + bc[c0 + i];
    o[i] = (_Float16)(v > 0.f ? v : (__expf(v) - 1.f));   // elu
  }
  *(h4*)&out[(size_t)node * HC + c0] = o;
}

// ---------------------------------------------------------------- pooling + MLP

__global__ __launch_bounds__(256) void gbound_kernel(const int* __restrict__ batch,
                                                     int* __restrict__ gstart, int n) {
  int g = blockIdx.x * 256 + threadIdx.x;
  if (g > GNUM) return;
  int lo = 0, hi = n;
  while (lo < hi) {
    int mid = (lo + hi) >> 1;
    if (batch[mid] < g) lo = mid + 1; else hi = mid;
  }
  gstart[g] = lo;
}

__global__ __launch_bounds__(256) void pool2_kernel(const _Float16* __restrict__ h,
                                                    const int* __restrict__ gstart,
                                                    float* __restrict__ gmean) {
  __shared__ float red[256];
  int g = blockIdx.x;
  int t = threadIdx.x;
  int s = gstart[g], e = gstart[g + 1];
  int c = t & 31, rg = t >> 5;
  float acc = 0.f;
  for (int i = s + rg; i < e; i += 8) acc += (float)h[(size_t)i * 32 + c];
  red[t] = acc;
  __syncthreads();
  if (t < 128) red[t] += red[t + 128];
  __syncthreads();
  if (t < 64) red[t] += red[t + 64];
  __syncthreads();
  if (t < 32) {
    float v = red[t] + red[t + 32];
    gmean[g * 32 + t] = v / fmaxf((float)(e - s), 1.f);
  }
}

__global__ __launch_bounds__(64) void fc_kernel(const float* __restrict__ gmean,
                                                const float* __restrict__ w1,
                                                const float* __restrict__ b1,
                                                const float* __restrict__ w2,
                                                const float* __restrict__ b2,
                                                float* __restrict__ out) {
  __shared__ float g[32];
  __shared__ float a1[64];
  int gi = blockIdx.x;
  int t = threadIdx.x;
  if (t < 32) g[t] = gmean[gi * 32 + t];
  __syncthreads();
  float v = b1[t];
  for (int k = 0; k < 32; k++) v += g[k] * w1[k * 64 + t];
  a1[t] = v > 0.f ? v : (__expf(v) - 1.f);
  __syncthreads();
  if (t < 4) {
    float o = b2[t];
    for (int k = 0; k < 64; k++) o += a1[k] * w2[k * 4 + t];
    out[gi * 4 + t] = o;
  }
}

// ---------------------------------------------------------------- launch

extern "C" void kernel_launch(void* const* d_in, const int* in_sizes, int n_in,
                              void* d_out, int out_size, void* d_ws, size_t ws_size,
                              hipStream_t stream) {
  const float* x     = (const float*)d_in[0];
  const int*   ei    = (const int*)d_in[1];
  const float* eattr = (const float*)d_in[2];
  const int*   batch = (const int*)d_in[3];
  const float *wl1 = (const float*)d_in[4],  *bl1 = (const float*)d_in[5];
  const float *wr1 = (const float*)d_in[6],  *br1 = (const float*)d_in[7];
  const float *we1 = (const float*)d_in[8],  *at1 = (const float*)d_in[9];
  const float *bc1 = (const float*)d_in[10];
  const float *wl2 = (const float*)d_in[11], *bl2 = (const float*)d_in[12];
  const float *wr2 = (const float*)d_in[13], *br2 = (const float*)d_in[14];
  const float *we2 = (const float*)d_in[15], *at2 = (const float*)d_in[16];
  const float *bc2 = (const float*)d_in[17];
  const float *wl3 = (const float*)d_in[18], *bl3 = (const float*)d_in[19];
  const float *wr3 = (const float*)d_in[20], *br3 = (const float*)d_in[21];
  const float *we3 = (const float*)d_in[22], *at3 = (const float*)d_in[23];
  const float *bc3 = (const float*)d_in[24];
  const float *wf1 = (const float*)d_in[25], *bf1 = (const float*)d_in[26];
  const float *wf2 = (const float*)d_in[27], *bf2 = (const float*)d_in[28];

  int N = in_sizes[0] / 16;
  int E = in_sizes[1] / 2;
  const int* srcp = ei;
  const int* dstp = ei + E;
  int EA = E + N;   // CSR entries incl. self-loops
  int NB = (N + 511) / 512;   // scan blocks (<=1024)

  char* wsb = (char*)d_ws;
  size_t off = 0;
  auto alloc = [&](size_t bytes) -> char* {
    char* p = wsb + off;
    off += (bytes + 255) & ~(size_t)255;
    return p;
  };
  int*       cnt     = (int*)alloc((size_t)N * 4);
  int*       row_ptr = (int*)alloc((size_t)(N + 1) * 4);
  int*       fill    = (int*)alloc((size_t)N * 4);
  int*       bpart   = (int*)alloc((size_t)1024 * 4);
  int*       boff    = (int*)alloc((size_t)1024 * 4);
  int*       csr_src = (int*)alloc((size_t)EA * 4);
  _Float16*  ea_csr  = (_Float16*)alloc((size_t)EA * 8 * 2);
  _Float16*  xl      = (_Float16*)alloc((size_t)N * 128 * 2);
  _Float16*  xr      = (_Float16*)alloc((size_t)N * 128 * 2);
  _Float16*  h16     = (_Float16*)alloc((size_t)N * 128 * 2);
  _Float16*  h3      = (_Float16*)alloc((size_t)N * 32 * 2);
  float*     gmean   = (float*)alloc((size_t)GNUM * 32 * 4);
  int*       gstart  = (int*)alloc((size_t)(GNUM + 1) * 4);
  _Float16*  wp2l    = (_Float16*)alloc((size_t)128 * 128 * 2);
  _Float16*  wp2r    = (_Float16*)alloc((size_t)128 * 128 * 2);
  _Float16*  wp3l    = (_Float16*)alloc((size_t)128 * 32 * 2);
  _Float16*  wp3r    = (_Float16*)alloc((size_t)128 * 32 * 2);

  hipMemsetAsync(cnt, 0, (size_t)N * 4, stream);

  hist_kernel<<<(E + 255) / 256, 256, 0, stream>>>(dstp, cnt, E);
  scan_part_kernel<<<NB, 256, 0, stream>>>(cnt, bpart, N);
  scan_top_kernel<<<1, 1024, 0, stream>>>(bpart, boff, row_ptr, NB, N);
  scan_write_kernel<<<NB, 256, 0, stream>>>(cnt, boff, row_ptr, fill, N);
  scatter_kernel<<<(E + 255) / 256, 256, 0, stream>>>(srcp, dstp, eattr, fill, csr_src, ea_csr, E);
  selfloop_kernel<<<(N + 255) / 256, 256, 0, stream>>>(row_ptr, csr_src, ea_csr, N);
  gbound_kernel<<<1, 256, 0, stream>>>(batch, gstart, N);
  pack_kernel<<<dim3(8, 2), 256, 0, stream>>>(wl2, wp2l, wr2, wp2r, 128, 128);
  pack_kernel<<<dim3(2, 2), 256, 0, stream>>>(wl3, wp3l, wr3, wp3r, 128, 32);

  // layer 1: K=16 -> 128 (f32 VALU, cheap)
  k1_kernel<16, 128><<<dim3((N + 63) / 64, 2), 256, 0, stream>>>(
      x, wl1, bl1, xl, wr1, br1, xr, N);
  k2_kernel<4><<<(N + 3) / 4, 128, 0, stream>>>(xl, xr, row_ptr, csr_src, ea_csr,
                                                we1, at1, bc1, h16, N);
  // layer 2: K=128 -> 128 (fp16 MFMA)
  k1m_kernel<128, 128><<<dim3((N + 63) / 64, 2), 256, 0, stream>>>(
      h16, wp2l, bl2, xl, wp2r, br2, xr, N);
  k2_kernel<4><<<(N + 3) / 4, 128, 0, stream>>>(xl, xr, row_ptr, csr_src, ea_csr,
                                                we2, at2, bc2, h16, N);
  // layer 3: K=128 -> 32 (fp16 MFMA, single head)
  k1m_kernel<128, 32><<<dim3((N + 63) / 64, 2), 256, 0, stream>>>(
      h16, wp3l, bl3, xl, wp3r, br3, xr, N);
  k2_kernel<1><<<(N + 15) / 16, 128, 0, stream>>>(xl, xr, row_ptr, csr_src, ea_csr,
                                                  we3, at3, bc3, h3, N);

  pool2_kernel<<<GNUM, 256, 0, stream>>>(h3, gstart, gmean);
  fc_kernel<<<GNUM, 64, 0, stream>>>(gmean, wf1, bf1, wf2, bf2, (float*)d_out);
}